// Round 7
// baseline (2557.211 us; speedup 1.0000x reference)
//
#include <hip/hip_runtime.h>
#include <hip/hip_bf16.h>

#define NN 100000   // nodes
#define NE 1600000  // edges
#define NG 100      // graphs
#define NPG 1000    // nodes per graph
#define CE 16       // edge channels
#define HH 64       // hidden
#define BN_SCALE 0.99999500003749959f  // 1/sqrt(1+1e-5)
#define NB 200          // edge-chunk blocks
#define ECH (NE / NB)   // 8000 edges per chunk
#define NBIN 400        // dst bins: bin = dst/250 (4 bins per graph)

// LESSON (R3): f32 global atomicAdd on gfx950 is a near-memory RMW (~35B HBM
// traffic each). LESSON (R5): even int global atomics cost ~40B each -> the
// 1.6M per-edge slot atomics WERE k_fill's 90us floor. This version builds the
// edge buckets with a counting sort: LDS histograms + scans, zero per-edge
// global atomics, one packed 8B store per edge.
// LESSON (R6): in lane-group edge processing, "count once per edge" guard must
// pick one CHANNEL lane (c==0), not lane-group 0 (s==0).

// ---- phase 1: per-chunk histogram over 400 dst-bins (LDS atomics only) ----
__global__ __launch_bounds__(256) void k_hist(const int* __restrict__ ei,
                                              int* __restrict__ hist) {
  __shared__ int h[NBIN];
  for (int i = threadIdx.x; i < NBIN; i += 256) h[i] = 0;
  __syncthreads();
  int e0 = blockIdx.x * ECH;
  for (int i = threadIdx.x; i < ECH; i += 256) {
    int d = ei[NE + e0 + i];
    atomicAdd(&h[d / 250], 1);
  }
  __syncthreads();
  for (int i = threadIdx.x; i < NBIN; i += 256) hist[blockIdx.x * NBIN + i] = h[i];
}

// ---- phase 2a: per-bin exclusive scan over the 200 chunk-counts ----
__global__ __launch_bounds__(256) void k_scan_a(const int* __restrict__ hist,
                                                int* __restrict__ partial,
                                                int* __restrict__ gtot) {
  __shared__ int sv[256];
  int bin = blockIdx.x, t = threadIdx.x;
  int v = (t < NB) ? hist[t * NBIN + bin] : 0;
  sv[t] = v;
  __syncthreads();
  for (int o = 1; o < 256; o <<= 1) {
    int a = (t >= o) ? sv[t - o] : 0;
    __syncthreads();
    sv[t] += a;
    __syncthreads();
  }
  if (t < NB) partial[t * NBIN + bin] = sv[t] - v;
  if (t == 255) gtot[bin] = sv[255];
}

// ---- phase 2b: exclusive scan of the 400 bin totals -> segment bases ----
__global__ __launch_bounds__(512) void k_scan_b(const int* __restrict__ gtot,
                                                int* __restrict__ gbase) {
  __shared__ int sv[512];
  int t = threadIdx.x;
  int v = (t < NBIN) ? gtot[t] : 0;
  sv[t] = v;
  __syncthreads();
  for (int o = 1; o < 512; o <<= 1) {
    int a = (t >= o) ? sv[t - o] : 0;
    __syncthreads();
    sv[t] += a;
    __syncthreads();
  }
  if (t < NBIN) gbase[t] = sv[t] - v;
  if (t == 511) gbase[NBIN] = sv[511];
}

// ---- phase 3: scatter edges into bin segments (LDS cursors, 1x 8B store) ----
// ebuf[pos] = eid<<32 | dst_local<<10 | src_local   (locals are within-graph)
__global__ __launch_bounds__(256) void k_bfill(const int* __restrict__ ei,
                                               const int* __restrict__ partial,
                                               const int* __restrict__ gbase,
                                               unsigned long long* __restrict__ ebuf) {
  __shared__ int cur[NBIN];
  int b = blockIdx.x;
  for (int i = threadIdx.x; i < NBIN; i += 256)
    cur[i] = gbase[i] + partial[b * NBIN + i];
  __syncthreads();
  int e0 = b * ECH;
  for (int i = threadIdx.x; i < ECH; i += 256) {
    int e = e0 + i;
    int d = ei[NE + e], s = ei[e];
    int bin = d / 250;
    int gb = (bin >> 2) * 1000;
    unsigned long long pk = (unsigned long long)(unsigned)e << 32 |
                            (unsigned)((d - gb) << 10) | (unsigned)(s - gb);
    int pos = atomicAdd(&cur[bin], 1);
    ebuf[pos] = pk;
  }
}

// ---- Se + cnt: per-500-node block, LDS f32 scatter, 16-lane-group ea pulls ----
// Se[n][c] = sum_{e: dst=n} edge_attr[e][c]; cnt[n] = in-degree.
__global__ __launch_bounds__(1024) void k_se2(
    const unsigned long long* __restrict__ ebuf, const int* __restrict__ gbase,
    const float* __restrict__ ea, float* __restrict__ Se, int* __restrict__ cnt) {
  __shared__ float se[500 * 16];
  __shared__ int cl[500];
  int m = blockIdx.x;  // dst range [m*500, (m+1)*500) = bins 2m, 2m+1
  for (int i = threadIdx.x; i < 8000; i += 1024) se[i] = 0.f;
  for (int i = threadIdx.x; i < 500; i += 1024) cl[i] = 0;
  __syncthreads();
  int lo = gbase[2 * m], hi = gbase[2 * m + 2];
  int nb = m * 500, g1000 = (m >> 1) * 1000;
  int lane = threadIdx.x & 63, wv = threadIdx.x >> 6;
  int s = lane >> 4, c = lane & 15;
  for (int ch = lo + wv * 64; ch < hi; ch += 16 * 64) {
    int idx = ch + lane;
    unsigned long long w = (idx < hi) ? ebuf[idx] : 0ULL;
#pragma unroll 4
    for (int st = 0; st < 16; ++st) {
      int j = (st << 2) | s;
      unsigned long long u = __shfl(w, j);
      bool ok = (ch + j) < hi;
      int ee = (int)(u >> 32);
      float v = ea[(size_t)ee * CE + c];  // 64B coalesced per 16-lane group
      int r = g1000 + (int)((u >> 10) & 1023) - nb;
      v = ok ? v : 0.f;
      r = ok ? r : 0;
      atomicAdd(&se[r * 16 + c], v);
      if (c == 0 && ok) atomicAdd(&cl[r], 1);  // one lane PER EDGE (R6 fix)
    }
  }
  __syncthreads();
  for (int i = threadIdx.x; i < 8000; i += 1024) Se[(size_t)nb * 16 + i] = se[i];
  for (int i = threadIdx.x; i < 500; i += 1024) cnt[nb + i] = cl[i];
}

// ---------------- per-layer node GEMM (unchanged structure) ----------------
// y[n][h] = x[n] @ W_j[:,h]  (bf16; message term)
// z[n][h] = (cnt[n]+1)*(x[n] @ W_i[:,h] + b[h]) + (Se[n] + ones) @ W_e[:,h]
#define GB 768
__global__ __launch_bounds__(256) void k_gemm(
    const float* __restrict__ x, const float* __restrict__ W,
    const float* __restrict__ b, const int* __restrict__ cnt,
    const float* __restrict__ Se, __hip_bfloat16* __restrict__ y,
    float* __restrict__ z) {
  __shared__ float Wl[144 * 64];
  __shared__ float bl[64];
  for (int i = threadIdx.x; i < 144 * 64; i += blockDim.x) Wl[i] = W[i];
  if (threadIdx.x < 64) bl[threadIdx.x] = b[threadIdx.x];
  __syncthreads();
  int lane = threadIdx.x & 63;
  float wi[64], wj[64], we[16];
#pragma unroll
  for (int k = 0; k < 64; ++k) wi[k] = Wl[k * 64 + lane];
#pragma unroll
  for (int k = 0; k < 64; ++k) wj[k] = Wl[(64 + k) * 64 + lane];
#pragma unroll
  for (int k = 0; k < 16; ++k) we[k] = Wl[(128 + k) * 64 + lane];
  float bv = bl[lane];
  float wesum = 0.f;  // self-loop edge_attr = ones
#pragma unroll
  for (int k = 0; k < 16; ++k) wesum += we[k];
  int wid = blockIdx.x * 4 + (threadIdx.x >> 6);
  const int nw = GB * 4;
  for (int n0 = wid; n0 < NN; n0 += nw) {
    int n = __builtin_amdgcn_readfirstlane(n0);  // wave-uniform -> s_load x row
    const float* xr = x + (size_t)n * HH;
    const float* sr = Se + (size_t)n * CE;
    float a0 = 0.f, a1 = 0.f, a2 = 0.f, a3 = 0.f;
    float c0 = 0.f, c1 = 0.f, c2 = 0.f, c3 = 0.f;
#pragma unroll
    for (int k = 0; k < 64; k += 4) {
      float x0 = xr[k], x1 = xr[k + 1], x2 = xr[k + 2], x3 = xr[k + 3];
      a0 = fmaf(x0, wj[k], a0);
      a1 = fmaf(x1, wj[k + 1], a1);
      a2 = fmaf(x2, wj[k + 2], a2);
      a3 = fmaf(x3, wj[k + 3], a3);
      c0 = fmaf(x0, wi[k], c0);
      c1 = fmaf(x1, wi[k + 1], c1);
      c2 = fmaf(x2, wi[k + 2], c2);
      c3 = fmaf(x3, wi[k + 3], c3);
    }
    float s0 = 0.f, s1 = 0.f;
#pragma unroll
    for (int k = 0; k < 16; k += 2) {
      s0 = fmaf(sr[k], we[k], s0);
      s1 = fmaf(sr[k + 1], we[k + 1], s1);
    }
    float deg = (float)(cnt[n] + 1);
    y[(size_t)n * HH + lane] = __float2bfloat16((a0 + a1) + (a2 + a3));
    z[(size_t)n * HH + lane] =
        deg * (((c0 + c1) + (c2 + c3)) + bv) + ((s0 + s1) + wesum);
  }
}

// ---- per-layer gather: LDS z-tile (250 nodes) + edge scatter, no atomics ----
// x_new[n] = relu(bn(relu(z[n] + y[n] + sum_{e:dst=n} y[src_e])))
__global__ __launch_bounds__(1024) void k_gath2(
    const __hip_bfloat16* __restrict__ y, const float* __restrict__ z,
    const unsigned long long* __restrict__ ebuf, const int* __restrict__ gbase,
    const float* __restrict__ gamma, const float* __restrict__ beta,
    float* __restrict__ xn, float* __restrict__ emb) {
  __shared__ float zl[250 * 64];  // 62.5 KB
  int bin = blockIdx.x;  // dst range [bin*250, ..+250)
  int nb = bin * 250, g1000 = (bin >> 2) * 1000;
  for (int i = threadIdx.x; i < 250 * 64; i += 1024)
    zl[i] = z[(size_t)nb * HH + i] + __bfloat162float(y[(size_t)nb * HH + i]);
  __syncthreads();
  int lo = gbase[bin], hi = gbase[bin + 1];
  int lane = threadIdx.x & 63, wv = threadIdx.x >> 6;
  for (int ch = lo + wv * 64; ch < hi; ch += 16 * 64) {
    int idx = ch + lane;
    unsigned long long w = (idx < hi) ? ebuf[idx] : 0ULL;
#pragma unroll 8
    for (int j = 0; j < 64; ++j) {
      unsigned long long u = __shfl(w, j);
      bool ok = (ch + j) < hi;
      int srcl = (int)(u & 1023);
      int r = (int)((u >> 10) & 1023) + g1000 - nb;
      float v = __bfloat162float(y[(size_t)(g1000 + srcl) * HH + lane]);
      v = ok ? v : 0.f;
      r = ok ? r : 0;
      atomicAdd(&zl[r * 64 + lane], v);  // ds_add_f32, CU-local
    }
  }
  __syncthreads();
  for (int i = threadIdx.x; i < 250 * 64; i += 1024) {
    int c = i & 63;
    float a = fmaxf(zl[i], 0.f);
    a = gamma[c] * a * BN_SCALE + beta[c];
    a = fmaxf(a, 0.f);
    xn[(size_t)nb * HH + i] = a;
    if ((bin & 3) == 0 && i < 64) emb[(bin >> 2) * HH + i] = a;  // spec node
  }
}

// ---------------- readout: pool + MLP ----------------
__global__ __launch_bounds__(256) void k_final(
    const float* __restrict__ xf, const float* __restrict__ emb,
    const float* __restrict__ nbr, const float* __restrict__ fc1w,
    const float* __restrict__ fc1b, const float* __restrict__ fc2w,
    const float* __restrict__ fc2b, float* __restrict__ out) {
  __shared__ float feats[320];
  __shared__ float pool4[4][64];
  __shared__ float r1[256];
  int g = blockIdx.x;
  int t = threadIdx.x;
  int lane = t & 63, w = t >> 6;
  if (t >= 64) {  // fill embs: feats[64..255]
    int j = t - 64;
    feats[64 + j] = emb[((size_t)(j >> 6) * NG + g) * HH + (j & 63)];
  }
  if (t < 64) feats[256 + t] = nbr[(size_t)g * HH + t];  // neighbor
  float acc = 0.f;
  for (int i = w; i < NPG; i += 4) acc += xf[(size_t)(g * NPG + i) * HH + lane];
  pool4[w][lane] = acc;
  __syncthreads();
  if (t < 64) feats[t] = pool4[0][t] + pool4[1][t] + pool4[2][t] + pool4[3][t];
  __syncthreads();
  float a = fc1b[t];
  for (int k = 0; k < 320; ++k) a = fmaf(feats[k], fc1w[k * 256 + t], a);
  r1[t] = fmaxf(a, 0.f);
  __syncthreads();
  if (t < 4) {
    float o = fc2b[t];
    for (int k = 0; k < 256; ++k) o = fmaf(r1[k], fc2w[k * 4 + t], o);
    out[g * 4 + t] = o;
  }
}

extern "C" void kernel_launch(void* const* d_in, const int* in_sizes, int n_in,
                              void* d_out, int out_size, void* d_ws, size_t ws_size,
                              hipStream_t stream) {
  const float* x     = (const float*)d_in[0];
  const float* eattr = (const float*)d_in[1];
  const float* nbr   = (const float*)d_in[2];
  const float* W     = (const float*)d_in[3];
  const float* b     = (const float*)d_in[4];
  const float* gamma = (const float*)d_in[5];
  const float* beta  = (const float*)d_in[6];
  const float* fc1w  = (const float*)d_in[7];
  const float* fc1b  = (const float*)d_in[8];
  const float* fc2w  = (const float*)d_in[9];
  const float* fc2b  = (const float*)d_in[10];
  const int*   ei    = (const int*)d_in[11];
  float* out = (float*)d_out;
  (void)in_sizes; (void)n_in; (void)out_size; (void)ws_size;

  char* p = (char*)d_ws;
  size_t off = 0;
  auto alloc = [&](size_t bytes) {
    char* q = p + off;
    off += (bytes + 255) & ~(size_t)255;
    return q;
  };
  int* hist    = (int*)alloc((size_t)NB * NBIN * 4);
  int* partial = (int*)alloc((size_t)NB * NBIN * 4);
  int* gtot    = (int*)alloc((size_t)NBIN * 4);
  int* gbase   = (int*)alloc((size_t)(NBIN + 1) * 4);
  unsigned long long* ebuf = (unsigned long long*)alloc((size_t)NE * 8);
  float* Se    = (float*)alloc((size_t)NN * CE * 4);
  int*   cnt   = (int*)alloc((size_t)NN * 4);
  __hip_bfloat16* ybuf = (__hip_bfloat16*)alloc((size_t)NN * HH * 2);
  float* zbuf  = (float*)alloc((size_t)NN * HH * 4);
  float* xA    = (float*)alloc((size_t)NN * HH * 4);
  float* xB    = (float*)alloc((size_t)NN * HH * 4);
  float* emb   = (float*)alloc((size_t)3 * NG * HH * 4);

  // CSR-free bucket build (no global atomics, no memsets needed)
  k_hist<<<NB, 256, 0, stream>>>(ei, hist);
  k_scan_a<<<NBIN, 256, 0, stream>>>(hist, partial, gtot);
  k_scan_b<<<1, 512, 0, stream>>>(gtot, gbase);
  k_bfill<<<NB, 256, 0, stream>>>(ei, partial, gbase, ebuf);
  k_se2<<<NBIN / 2, 1024, 0, stream>>>(ebuf, gbase, eattr, Se, cnt);

  // layer 0: x -> xA
  k_gemm<<<GB, 256, 0, stream>>>(x, W, b, cnt, Se, ybuf, zbuf);
  k_gath2<<<NBIN, 1024, 0, stream>>>(ybuf, zbuf, ebuf, gbase, gamma, beta, xA, emb);
  // layer 1: xA -> xB
  k_gemm<<<GB, 256, 0, stream>>>(xA, W + 144 * 64, b + 64, cnt, Se, ybuf, zbuf);
  k_gath2<<<NBIN, 1024, 0, stream>>>(ybuf, zbuf, ebuf, gbase, gamma + 64, beta + 64,
                                     xB, emb + NG * HH);
  // layer 2: xB -> xA
  k_gemm<<<GB, 256, 0, stream>>>(xB, W + 2 * 144 * 64, b + 128, cnt, Se, ybuf, zbuf);
  k_gath2<<<NBIN, 1024, 0, stream>>>(ybuf, zbuf, ebuf, gbase, gamma + 128, beta + 128,
                                     xA, emb + 2 * NG * HH);

  k_final<<<NG, 256, 0, stream>>>(xA, emb, nbr, fc1w, fc1b, fc2w, fc2b, out);
}

// Round 8
// 449.801 us; speedup vs baseline: 5.6852x; 5.6852x over previous
//
#include <hip/hip_runtime.h>
#include <hip/hip_bf16.h>

#define NN 100000   // nodes
#define NE 1600000  // edges
#define NG 100      // graphs
#define NPG 1000    // nodes per graph
#define CE 16       // edge channels
#define HH 64       // hidden
#define BN_SCALE 0.99999500003749959f  // 1/sqrt(1+1e-5)
#define NB 200          // edge-chunk blocks
#define ECH (NE / NB)   // 8000 edges per chunk
#define NBIN 400        // dst bins: bin = dst/250 (4 bins per graph)

// LESSON (R3): f32 global atomicAdd on gfx950 is a near-memory RMW (~35B HBM
// traffic each). LESSON (R5): int global atomics cost ~40B each -> 1.6M
// per-edge slot atomics were a 90us floor. Build CSR by counting sort instead.
// LESSON (R6): one-edge-per-wave-instruction LDS scatter (shfl broadcast +
// ds_add) is ~10x slower than wave-per-node REGISTER accumulation with 8-deep
// load ILP. Edge lists must be node-sorted so gather stays register-resident.

// ---- phase 1: per-chunk histogram over 400 dst-bins (LDS atomics only) ----
__global__ __launch_bounds__(256) void k_hist(const int* __restrict__ ei,
                                              int* __restrict__ hist) {
  __shared__ int h[NBIN];
  for (int i = threadIdx.x; i < NBIN; i += 256) h[i] = 0;
  __syncthreads();
  int e0 = blockIdx.x * ECH;
  for (int i = threadIdx.x; i < ECH; i += 256) {
    int d = ei[NE + e0 + i];
    atomicAdd(&h[d / 250], 1);
  }
  __syncthreads();
  for (int i = threadIdx.x; i < NBIN; i += 256) hist[blockIdx.x * NBIN + i] = h[i];
}

// ---- phase 2a: per-bin exclusive scan over the 200 chunk-counts ----
__global__ __launch_bounds__(256) void k_scan_a(const int* __restrict__ hist,
                                                int* __restrict__ partial,
                                                int* __restrict__ gtot) {
  __shared__ int sv[256];
  int bin = blockIdx.x, t = threadIdx.x;
  int v = (t < NB) ? hist[t * NBIN + bin] : 0;
  sv[t] = v;
  __syncthreads();
  for (int o = 1; o < 256; o <<= 1) {
    int a = (t >= o) ? sv[t - o] : 0;
    __syncthreads();
    sv[t] += a;
    __syncthreads();
  }
  if (t < NB) partial[t * NBIN + bin] = sv[t] - v;
  if (t == 255) gtot[bin] = sv[255];
}

// ---- phase 2b: exclusive scan of the 400 bin totals -> segment bases ----
__global__ __launch_bounds__(512) void k_scan_b(const int* __restrict__ gtot,
                                                int* __restrict__ gbase) {
  __shared__ int sv[512];
  int t = threadIdx.x;
  int v = (t < NBIN) ? gtot[t] : 0;
  sv[t] = v;
  __syncthreads();
  for (int o = 1; o < 512; o <<= 1) {
    int a = (t >= o) ? sv[t - o] : 0;
    __syncthreads();
    sv[t] += a;
    __syncthreads();
  }
  if (t < NBIN) gbase[t] = sv[t] - v;
  if (t == 511) gbase[NBIN] = sv[511];
}

// ---- phase 3: scatter edges into bin segments (LDS cursors, 1x 8B store) ----
// ebuf[pos] = eid<<32 | dst_local<<10 | src_local   (locals are within-graph)
__global__ __launch_bounds__(256) void k_bfill(const int* __restrict__ ei,
                                               const int* __restrict__ partial,
                                               const int* __restrict__ gbase,
                                               unsigned long long* __restrict__ ebuf) {
  __shared__ int cur[NBIN];
  int b = blockIdx.x;
  for (int i = threadIdx.x; i < NBIN; i += 256)
    cur[i] = gbase[i] + partial[b * NBIN + i];
  __syncthreads();
  int e0 = b * ECH;
  for (int i = threadIdx.x; i < ECH; i += 256) {
    int e = e0 + i;
    int d = ei[NE + e], s = ei[e];
    int bin = d / 250;
    int gb = (bin >> 2) * 1000;
    unsigned long long pk = (unsigned long long)(unsigned)e << 32 |
                            (unsigned)((d - gb) << 10) | (unsigned)(s - gb);
    int pos = atomicAdd(&cur[bin], 1);
    ebuf[pos] = pk;
  }
}

// ---- phase 4: within-bin counting sort by node -> per-node CSR ----
// ebuf2[pos] = eid<<10 | src_local (u32; eid<2^21, srcl<2^10)
// rowptr[n]..rowptr[n+1] = node n's edge segment; cnt[n] = in-degree.
__global__ __launch_bounds__(256) void k_nsort(
    const unsigned long long* __restrict__ ebuf, const int* __restrict__ gbase,
    unsigned* __restrict__ ebuf2, int* __restrict__ rowptr,
    int* __restrict__ cnt) {
  __shared__ int h[250];
  __shared__ int cur[250];
  __shared__ int sv[256];
  int bin = blockIdx.x, t = threadIdx.x;
  int nb = bin * 250, lbase = (bin & 3) * 250;
  int lo = gbase[bin], hi = gbase[bin + 1];
  if (t < 250) h[t] = 0;
  __syncthreads();
  for (int i = lo + t; i < hi; i += 256) {
    int dl = (int)((ebuf[i] >> 10) & 1023);
    atomicAdd(&h[dl - lbase], 1);
  }
  __syncthreads();
  int v = (t < 250) ? h[t] : 0;
  sv[t] = v;
  __syncthreads();
  for (int o = 1; o < 256; o <<= 1) {
    int a = (t >= o) ? sv[t - o] : 0;
    __syncthreads();
    sv[t] += a;
    __syncthreads();
  }
  if (t < 250) {
    int base = lo + sv[t] - v;  // exclusive
    rowptr[nb + t] = base;
    cur[t] = base;
    cnt[nb + t] = v;
  }
  if (bin == NBIN - 1 && t == 0) rowptr[NN] = hi;
  __syncthreads();
  for (int i = lo + t; i < hi; i += 256) {
    unsigned long long u = ebuf[i];
    int dl = (int)((u >> 10) & 1023);
    unsigned pk = (unsigned)(u >> 32) << 10 | (unsigned)(u & 1023);
    int pos = atomicAdd(&cur[dl - lbase], 1);
    ebuf2[pos] = pk;
  }
}

// ---- Se[n][c] = sum_{e:dst=n} ea[e][c]: wave-per-node, 4 slots x 16 ch ----
// 16 edges/iteration (4 loads per lane in flight); shfl_xor cross-slot reduce.
#define SEB 25000  // 4 waves/block, wave-per-node; 25000 = 8 * 3125
__global__ __launch_bounds__(256) void k_se3(const unsigned* __restrict__ ebuf2,
                                             const int* __restrict__ rowptr,
                                             const float* __restrict__ ea,
                                             float* __restrict__ Se) {
  int lane = threadIdx.x & 63;
  int s = lane >> 4, c = lane & 15;
  int orig = blockIdx.x;
  int blk = (orig & 7) * (SEB / 8) + (orig >> 3);  // XCD-contiguous mapping
  int n0 = blk * 4 + (threadIdx.x >> 6);
  if (n0 >= NN) return;
  int n = __builtin_amdgcn_readfirstlane(n0);
  int lo = rowptr[n], hi = rowptr[n + 1];
  float acc = 0.f;
  for (int k0 = lo; k0 < hi; k0 += 16) {
    int k1 = k0 + s, k2 = k0 + 4 + s, k3 = k0 + 8 + s, k4 = k0 + 12 + s;
    float v1 = 0.f, v2 = 0.f, v3 = 0.f, v4 = 0.f;
    if (k1 < hi) v1 = ea[(size_t)(ebuf2[k1] >> 10) * CE + c];
    if (k2 < hi) v2 = ea[(size_t)(ebuf2[k2] >> 10) * CE + c];
    if (k3 < hi) v3 = ea[(size_t)(ebuf2[k3] >> 10) * CE + c];
    if (k4 < hi) v4 = ea[(size_t)(ebuf2[k4] >> 10) * CE + c];
    acc += (v1 + v2) + (v3 + v4);
  }
  acc += __shfl_xor(acc, 16);
  acc += __shfl_xor(acc, 32);
  if (lane < 16) Se[(size_t)n * CE + lane] = acc;
}

// ---------------- per-layer node GEMM ----------------
// y[n][h] = x[n] @ W_j[:,h]  (bf16; message term)
// z[n][h] = (cnt[n]+1)*(x[n] @ W_i[:,h] + b[h]) + (Se[n] + ones) @ W_e[:,h]
#define GB 768
__global__ __launch_bounds__(256) void k_gemm(
    const float* __restrict__ x, const float* __restrict__ W,
    const float* __restrict__ b, const int* __restrict__ cnt,
    const float* __restrict__ Se, __hip_bfloat16* __restrict__ y,
    float* __restrict__ z) {
  __shared__ float Wl[144 * 64];
  __shared__ float bl[64];
  for (int i = threadIdx.x; i < 144 * 64; i += blockDim.x) Wl[i] = W[i];
  if (threadIdx.x < 64) bl[threadIdx.x] = b[threadIdx.x];
  __syncthreads();
  int lane = threadIdx.x & 63;
  float wi[64], wj[64], we[16];
#pragma unroll
  for (int k = 0; k < 64; ++k) wi[k] = Wl[k * 64 + lane];
#pragma unroll
  for (int k = 0; k < 64; ++k) wj[k] = Wl[(64 + k) * 64 + lane];
#pragma unroll
  for (int k = 0; k < 16; ++k) we[k] = Wl[(128 + k) * 64 + lane];
  float bv = bl[lane];
  float wesum = 0.f;  // self-loop edge_attr = ones
#pragma unroll
  for (int k = 0; k < 16; ++k) wesum += we[k];
  int wid = blockIdx.x * 4 + (threadIdx.x >> 6);
  const int nw = GB * 4;
  for (int n0 = wid; n0 < NN; n0 += nw) {
    int n = __builtin_amdgcn_readfirstlane(n0);  // wave-uniform -> s_load x row
    const float* xr = x + (size_t)n * HH;
    const float* sr = Se + (size_t)n * CE;
    float a0 = 0.f, a1 = 0.f, a2 = 0.f, a3 = 0.f;
    float c0 = 0.f, c1 = 0.f, c2 = 0.f, c3 = 0.f;
#pragma unroll
    for (int k = 0; k < 64; k += 4) {
      float x0 = xr[k], x1 = xr[k + 1], x2 = xr[k + 2], x3 = xr[k + 3];
      a0 = fmaf(x0, wj[k], a0);
      a1 = fmaf(x1, wj[k + 1], a1);
      a2 = fmaf(x2, wj[k + 2], a2);
      a3 = fmaf(x3, wj[k + 3], a3);
      c0 = fmaf(x0, wi[k], c0);
      c1 = fmaf(x1, wi[k + 1], c1);
      c2 = fmaf(x2, wi[k + 2], c2);
      c3 = fmaf(x3, wi[k + 3], c3);
    }
    float s0 = 0.f, s1 = 0.f;
#pragma unroll
    for (int k = 0; k < 16; k += 2) {
      s0 = fmaf(sr[k], we[k], s0);
      s1 = fmaf(sr[k + 1], we[k + 1], s1);
    }
    float deg = (float)(cnt[n] + 1);
    y[(size_t)n * HH + lane] = __float2bfloat16((a0 + a1) + (a2 + a3));
    z[(size_t)n * HH + lane] =
        deg * (((c0 + c1) + (c2 + c3)) + bv) + ((s0 + s1) + wesum);
  }
}

// ---- per-layer gather: wave-per-node, register accumulate, 8-deep ILP ----
// x_new[n] = relu(bn(relu(z[n] + y[n] + sum_{e:dst=n} y[src_e])))
#define GTB 25000  // 4 waves/block, wave-per-node; 25000 = 8 * 3125
__global__ __launch_bounds__(256) void k_gath3(
    const __hip_bfloat16* __restrict__ y, const float* __restrict__ z,
    const unsigned* __restrict__ ebuf2, const int* __restrict__ rowptr,
    const float* __restrict__ gamma, const float* __restrict__ beta,
    float* __restrict__ xn, float* __restrict__ emb) {
  int lane = threadIdx.x & 63;
  int orig = blockIdx.x;
  int blk = (orig & 7) * (GTB / 8) + (orig >> 3);  // XCD-contiguous mapping
  int n0 = blk * 4 + (threadIdx.x >> 6);
  if (n0 >= NN) return;
  int n = __builtin_amdgcn_readfirstlane(n0);
  int lo = rowptr[n], hi = rowptr[n + 1];
  int deg = hi - lo;
  int gb = (n / NPG) * NPG;  // graph base node
  const unsigned* cl = ebuf2 + lo;  // wave-uniform
  const __hip_bfloat16* yg = y + (size_t)gb * HH;
  float acc = z[(size_t)n * HH + lane] +
              __bfloat162float(y[(size_t)n * HH + lane]);  // local + self-loop
  int k = 0;
  for (; k + 8 <= deg; k += 8) {
    int s0 = cl[k] & 1023, s1 = cl[k + 1] & 1023;
    int s2 = cl[k + 2] & 1023, s3 = cl[k + 3] & 1023;
    int s4 = cl[k + 4] & 1023, s5 = cl[k + 5] & 1023;
    int s6 = cl[k + 6] & 1023, s7 = cl[k + 7] & 1023;
    float v0 = __bfloat162float(yg[(size_t)s0 * HH + lane]);
    float v1 = __bfloat162float(yg[(size_t)s1 * HH + lane]);
    float v2 = __bfloat162float(yg[(size_t)s2 * HH + lane]);
    float v3 = __bfloat162float(yg[(size_t)s3 * HH + lane]);
    float v4 = __bfloat162float(yg[(size_t)s4 * HH + lane]);
    float v5 = __bfloat162float(yg[(size_t)s5 * HH + lane]);
    float v6 = __bfloat162float(yg[(size_t)s6 * HH + lane]);
    float v7 = __bfloat162float(yg[(size_t)s7 * HH + lane]);
    acc += ((v0 + v1) + (v2 + v3)) + ((v4 + v5) + (v6 + v7));
  }
  for (; k < deg; ++k)
    acc += __bfloat162float(yg[(size_t)(cl[k] & 1023) * HH + lane]);
  acc = fmaxf(acc, 0.f);                            // relu inside MP layer
  acc = gamma[lane] * acc * BN_SCALE + beta[lane];  // eval BN
  acc = fmaxf(acc, 0.f);                            // relu after BN
  xn[(size_t)n * HH + lane] = acc;
  if (n % NPG == 0) emb[(n / NPG) * HH + lane] = acc;  // spec_idx = g*NPG
}

// ---------------- readout: pool + MLP ----------------
__global__ __launch_bounds__(256) void k_final(
    const float* __restrict__ xf, const float* __restrict__ emb,
    const float* __restrict__ nbr, const float* __restrict__ fc1w,
    const float* __restrict__ fc1b, const float* __restrict__ fc2w,
    const float* __restrict__ fc2b, float* __restrict__ out) {
  __shared__ float feats[320];
  __shared__ float pool4[4][64];
  __shared__ float r1[256];
  int g = blockIdx.x;
  int t = threadIdx.x;
  int lane = t & 63, w = t >> 6;
  if (t >= 64) {  // fill embs: feats[64..255]
    int j = t - 64;
    feats[64 + j] = emb[((size_t)(j >> 6) * NG + g) * HH + (j & 63)];
  }
  if (t < 64) feats[256 + t] = nbr[(size_t)g * HH + t];  // neighbor
  float acc = 0.f;
  for (int i = w; i < NPG; i += 4) acc += xf[(size_t)(g * NPG + i) * HH + lane];
  pool4[w][lane] = acc;
  __syncthreads();
  if (t < 64) feats[t] = pool4[0][t] + pool4[1][t] + pool4[2][t] + pool4[3][t];
  __syncthreads();
  float a = fc1b[t];
  for (int k = 0; k < 320; ++k) a = fmaf(feats[k], fc1w[k * 256 + t], a);
  r1[t] = fmaxf(a, 0.f);
  __syncthreads();
  if (t < 4) {
    float o = fc2b[t];
    for (int k = 0; k < 256; ++k) o = fmaf(r1[k], fc2w[k * 4 + t], o);
    out[g * 4 + t] = o;
  }
}

extern "C" void kernel_launch(void* const* d_in, const int* in_sizes, int n_in,
                              void* d_out, int out_size, void* d_ws, size_t ws_size,
                              hipStream_t stream) {
  const float* x     = (const float*)d_in[0];
  const float* eattr = (const float*)d_in[1];
  const float* nbr   = (const float*)d_in[2];
  const float* W     = (const float*)d_in[3];
  const float* b     = (const float*)d_in[4];
  const float* gamma = (const float*)d_in[5];
  const float* beta  = (const float*)d_in[6];
  const float* fc1w  = (const float*)d_in[7];
  const float* fc1b  = (const float*)d_in[8];
  const float* fc2w  = (const float*)d_in[9];
  const float* fc2b  = (const float*)d_in[10];
  const int*   ei    = (const int*)d_in[11];
  float* out = (float*)d_out;
  (void)in_sizes; (void)n_in; (void)out_size; (void)ws_size;

  char* p = (char*)d_ws;
  size_t off = 0;
  auto alloc = [&](size_t bytes) {
    char* q = p + off;
    off += (bytes + 255) & ~(size_t)255;
    return q;
  };
  int* hist    = (int*)alloc((size_t)NB * NBIN * 4);
  int* partial = (int*)alloc((size_t)NB * NBIN * 4);
  int* gtot    = (int*)alloc((size_t)NBIN * 4);
  int* gbase   = (int*)alloc((size_t)(NBIN + 1) * 4);
  unsigned long long* ebuf = (unsigned long long*)alloc((size_t)NE * 8);
  unsigned* ebuf2 = (unsigned*)alloc((size_t)NE * 4);
  int* rowptr  = (int*)alloc((size_t)(NN + 1) * 4);
  float* Se    = (float*)alloc((size_t)NN * CE * 4);
  int*   cnt   = (int*)alloc((size_t)NN * 4);
  __hip_bfloat16* ybuf = (__hip_bfloat16*)alloc((size_t)NN * HH * 2);
  float* zbuf  = (float*)alloc((size_t)NN * HH * 4);
  float* xA    = (float*)alloc((size_t)NN * HH * 4);
  float* xB    = (float*)alloc((size_t)NN * HH * 4);
  float* emb   = (float*)alloc((size_t)3 * NG * HH * 4);

  // CSR build via two-level counting sort (zero global atomics, no memsets)
  k_hist<<<NB, 256, 0, stream>>>(ei, hist);
  k_scan_a<<<NBIN, 256, 0, stream>>>(hist, partial, gtot);
  k_scan_b<<<1, 512, 0, stream>>>(gtot, gbase);
  k_bfill<<<NB, 256, 0, stream>>>(ei, partial, gbase, ebuf);
  k_nsort<<<NBIN, 256, 0, stream>>>(ebuf, gbase, ebuf2, rowptr, cnt);
  k_se3<<<SEB, 256, 0, stream>>>(ebuf2, rowptr, eattr, Se);

  // layer 0: x -> xA
  k_gemm<<<GB, 256, 0, stream>>>(x, W, b, cnt, Se, ybuf, zbuf);
  k_gath3<<<GTB, 256, 0, stream>>>(ybuf, zbuf, ebuf2, rowptr, gamma, beta, xA, emb);
  // layer 1: xA -> xB
  k_gemm<<<GB, 256, 0, stream>>>(xA, W + 144 * 64, b + 64, cnt, Se, ybuf, zbuf);
  k_gath3<<<GTB, 256, 0, stream>>>(ybuf, zbuf, ebuf2, rowptr, gamma + 64, beta + 64,
                                   xB, emb + NG * HH);
  // layer 2: xB -> xA
  k_gemm<<<GB, 256, 0, stream>>>(xB, W + 2 * 144 * 64, b + 128, cnt, Se, ybuf, zbuf);
  k_gath3<<<GTB, 256, 0, stream>>>(ybuf, zbuf, ebuf2, rowptr, gamma + 128, beta + 128,
                                   xA, emb + 2 * NG * HH);

  k_final<<<NG, 256, 0, stream>>>(xA, emb, nbr, fc1w, fc1b, fc2w, fc2b, out);
}

// Round 9
// 418.728 us; speedup vs baseline: 6.1071x; 1.0742x over previous
//
#include <hip/hip_runtime.h>
#include <hip/hip_bf16.h>

#define NN 100000   // nodes
#define NE 1600000  // edges
#define NG 100      // graphs
#define NPG 1000    // nodes per graph
#define CE 16       // edge channels
#define HH 64       // hidden
#define BN_SCALE 0.99999500003749959f  // 1/sqrt(1+1e-5)
#define NB 200          // edge-chunk blocks
#define ECH (NE / NB)   // 8000 edges per chunk
#define NBIN 400        // dst bins: bin = dst/250 (4 bins per graph)
#define NRANGE 12500    // nodes per XCD range

// LESSON (R3): f32 global atomicAdd on gfx950 = near-memory RMW (~35B HBM each).
// LESSON (R5): int global atomics ~40B each -> counting-sort CSR, no atomics.
// LESSON (R6): edge-per-wave-instruction LDS scatter is ~10x slower than
// wave-per-node register accumulation with 8-deep load ILP.
// LESSON (R8): a "register cache" of W read from LDS stays IN LDS if the
// compiler targets occupancy (VGPR=84 observed): 144 ds_read/node serialized
// on the LDS pipe. Fix: no LDS, coalesced global W loads + launch_bounds(,1).

// ---- phase 1: per-chunk histogram over 400 dst-bins (LDS atomics only) ----
__global__ __launch_bounds__(256) void k_hist(const int* __restrict__ ei,
                                              int* __restrict__ hist) {
  __shared__ int h[NBIN];
  for (int i = threadIdx.x; i < NBIN; i += 256) h[i] = 0;
  __syncthreads();
  int e0 = blockIdx.x * ECH;
  for (int i = threadIdx.x; i < ECH; i += 256) {
    int d = ei[NE + e0 + i];
    atomicAdd(&h[d / 250], 1);
  }
  __syncthreads();
  for (int i = threadIdx.x; i < NBIN; i += 256) hist[blockIdx.x * NBIN + i] = h[i];
}

// ---- phase 2a: per-bin exclusive scan over the 200 chunk-counts ----
__global__ __launch_bounds__(256) void k_scan_a(const int* __restrict__ hist,
                                                int* __restrict__ partial,
                                                int* __restrict__ gtot) {
  __shared__ int sv[256];
  int bin = blockIdx.x, t = threadIdx.x;
  int v = (t < NB) ? hist[t * NBIN + bin] : 0;
  sv[t] = v;
  __syncthreads();
  for (int o = 1; o < 256; o <<= 1) {
    int a = (t >= o) ? sv[t - o] : 0;
    __syncthreads();
    sv[t] += a;
    __syncthreads();
  }
  if (t < NB) partial[t * NBIN + bin] = sv[t] - v;
  if (t == 255) gtot[bin] = sv[255];
}

// ---- phase 2b: exclusive scan of the 400 bin totals -> segment bases ----
__global__ __launch_bounds__(512) void k_scan_b(const int* __restrict__ gtot,
                                                int* __restrict__ gbase) {
  __shared__ int sv[512];
  int t = threadIdx.x;
  int v = (t < NBIN) ? gtot[t] : 0;
  sv[t] = v;
  __syncthreads();
  for (int o = 1; o < 512; o <<= 1) {
    int a = (t >= o) ? sv[t - o] : 0;
    __syncthreads();
    sv[t] += a;
    __syncthreads();
  }
  if (t < NBIN) gbase[t] = sv[t] - v;
  if (t == 511) gbase[NBIN] = sv[511];
}

// ---- phase 3: scatter edges into bin segments (LDS cursors, 1x 8B store) ----
// ebuf[pos] = eid<<32 | dst_local<<10 | src_local   (locals are within-graph)
__global__ __launch_bounds__(256) void k_bfill(const int* __restrict__ ei,
                                               const int* __restrict__ partial,
                                               const int* __restrict__ gbase,
                                               unsigned long long* __restrict__ ebuf) {
  __shared__ int cur[NBIN];
  int b = blockIdx.x;
  for (int i = threadIdx.x; i < NBIN; i += 256)
    cur[i] = gbase[i] + partial[b * NBIN + i];
  __syncthreads();
  int e0 = b * ECH;
  for (int i = threadIdx.x; i < ECH; i += 256) {
    int e = e0 + i;
    int d = ei[NE + e], s = ei[e];
    int bin = d / 250;
    int gb = (bin >> 2) * 1000;
    unsigned long long pk = (unsigned long long)(unsigned)e << 32 |
                            (unsigned)((d - gb) << 10) | (unsigned)(s - gb);
    int pos = atomicAdd(&cur[bin], 1);
    ebuf[pos] = pk;
  }
}

// ---- phase 4: within-bin counting sort by node -> per-node CSR ----
// ebuf2[pos] = eid<<10 | src_local (u32); rowptr[n]..rowptr[n+1]; cnt = deg
__global__ __launch_bounds__(256) void k_nsort(
    const unsigned long long* __restrict__ ebuf, const int* __restrict__ gbase,
    unsigned* __restrict__ ebuf2, int* __restrict__ rowptr,
    int* __restrict__ cnt) {
  __shared__ int h[250];
  __shared__ int cur[250];
  __shared__ int sv[256];
  int bin = blockIdx.x, t = threadIdx.x;
  int nb = bin * 250, lbase = (bin & 3) * 250;
  int lo = gbase[bin], hi = gbase[bin + 1];
  if (t < 250) h[t] = 0;
  __syncthreads();
  for (int i = lo + t; i < hi; i += 256) {
    int dl = (int)((ebuf[i] >> 10) & 1023);
    atomicAdd(&h[dl - lbase], 1);
  }
  __syncthreads();
  int v = (t < 250) ? h[t] : 0;
  sv[t] = v;
  __syncthreads();
  for (int o = 1; o < 256; o <<= 1) {
    int a = (t >= o) ? sv[t - o] : 0;
    __syncthreads();
    sv[t] += a;
    __syncthreads();
  }
  if (t < 250) {
    int base = lo + sv[t] - v;  // exclusive
    rowptr[nb + t] = base;
    cur[t] = base;
    cnt[nb + t] = v;
  }
  if (bin == NBIN - 1 && t == 0) rowptr[NN] = hi;
  __syncthreads();
  for (int i = lo + t; i < hi; i += 256) {
    unsigned long long u = ebuf[i];
    int dl = (int)((u >> 10) & 1023);
    unsigned pk = (unsigned)(u >> 32) << 10 | (unsigned)(u & 1023);
    int pos = atomicAdd(&cur[dl - lbase], 1);
    ebuf2[pos] = pk;
  }
}

// ---- Se[n][c] = sum_{e:dst=n} ea[e][c]: wave-per-node, 4 slots x 16 ch ----
#define SEB 25000  // 4 waves/block, wave-per-node; 25000 = 8 * 3125
__global__ __launch_bounds__(256) void k_se3(const unsigned* __restrict__ ebuf2,
                                             const int* __restrict__ rowptr,
                                             const float* __restrict__ ea,
                                             float* __restrict__ Se) {
  int lane = threadIdx.x & 63;
  int s = lane >> 4, c = lane & 15;
  int orig = blockIdx.x;
  int blk = (orig & 7) * (SEB / 8) + (orig >> 3);  // XCD-contiguous mapping
  int n0 = blk * 4 + (threadIdx.x >> 6);
  if (n0 >= NN) return;
  int n = __builtin_amdgcn_readfirstlane(n0);
  int lo = rowptr[n], hi = rowptr[n + 1];
  float acc = 0.f;
  for (int k0 = lo; k0 < hi; k0 += 16) {
    int k1 = k0 + s, k2 = k0 + 4 + s, k3 = k0 + 8 + s, k4 = k0 + 12 + s;
    float v1 = 0.f, v2 = 0.f, v3 = 0.f, v4 = 0.f;
    if (k1 < hi) v1 = ea[(size_t)(ebuf2[k1] >> 10) * CE + c];
    if (k2 < hi) v2 = ea[(size_t)(ebuf2[k2] >> 10) * CE + c];
    if (k3 < hi) v3 = ea[(size_t)(ebuf2[k3] >> 10) * CE + c];
    if (k4 < hi) v4 = ea[(size_t)(ebuf2[k4] >> 10) * CE + c];
    acc += (v1 + v2) + (v3 + v4);
  }
  acc += __shfl_xor(acc, 16);
  acc += __shfl_xor(acc, 32);
  if (lane < 16) Se[(size_t)n * CE + lane] = acc;
}

// ---------------- per-layer node GEMM: no LDS, W columns in VGPRs ----------
// y[n][h] = x[n] @ W_j[:,h]  (bf16)
// z[n][h] = (cnt[n]+1)*(x[n] @ W_i[:,h] + b[h]) + (Se[n]+ones) @ W_e[:,h] (bf16)
// x row via wave-uniform s_load (SGPRs); W via coalesced global loads -> VGPRs.
#define GB 1024  // 128 blocks per XCD range
template <typename T>
__global__ __launch_bounds__(256, 1) void k_gemm(
    const T* __restrict__ x, const float* __restrict__ W,
    const float* __restrict__ b, const int* __restrict__ cnt,
    const float* __restrict__ Se, __hip_bfloat16* __restrict__ y,
    __hip_bfloat16* __restrict__ z) {
  int lane = threadIdx.x & 63;
  float wi[64], wj[64], we[16];
#pragma unroll
  for (int k = 0; k < 64; ++k) wi[k] = W[k * 64 + lane];
#pragma unroll
  for (int k = 0; k < 64; ++k) wj[k] = W[(64 + k) * 64 + lane];
#pragma unroll
  for (int k = 0; k < 16; ++k) we[k] = W[(128 + k) * 64 + lane];
  float bv = b[lane];
  float wesum = 0.f;  // self-loop edge_attr = ones
#pragma unroll
  for (int k = 0; k < 16; ++k) wesum += we[k];
  int xcd = blockIdx.x & 7;
  int wid = (blockIdx.x >> 3) * 4 + (threadIdx.x >> 6);  // 0..511 in range
  int lo = xcd * NRANGE, hi = lo + NRANGE;
  const int stride = (GB / 8) * 4;
  for (int n0 = lo + wid; n0 < hi; n0 += stride) {
    int n = __builtin_amdgcn_readfirstlane(n0);  // wave-uniform -> s_load row
    float xv[64];  // uniform values -> SGPRs
    if constexpr (sizeof(T) == 4) {
      const float* xr = (const float*)x + (size_t)n * HH;
#pragma unroll
      for (int k = 0; k < 64; ++k) xv[k] = xr[k];
    } else {
      const unsigned* xr = (const unsigned*)((const T*)x + (size_t)n * HH);
#pragma unroll
      for (int k2 = 0; k2 < 32; ++k2) {
        unsigned u = xr[k2];
        xv[2 * k2] = __uint_as_float(u << 16);
        xv[2 * k2 + 1] = __uint_as_float(u & 0xffff0000u);
      }
    }
    const float* sr = Se + (size_t)n * CE;
    float a0 = 0.f, a1 = 0.f, a2 = 0.f, a3 = 0.f;
    float c0 = 0.f, c1 = 0.f, c2 = 0.f, c3 = 0.f;
#pragma unroll
    for (int k = 0; k < 64; k += 4) {
      a0 = fmaf(xv[k], wj[k], a0);
      a1 = fmaf(xv[k + 1], wj[k + 1], a1);
      a2 = fmaf(xv[k + 2], wj[k + 2], a2);
      a3 = fmaf(xv[k + 3], wj[k + 3], a3);
      c0 = fmaf(xv[k], wi[k], c0);
      c1 = fmaf(xv[k + 1], wi[k + 1], c1);
      c2 = fmaf(xv[k + 2], wi[k + 2], c2);
      c3 = fmaf(xv[k + 3], wi[k + 3], c3);
    }
    float s0 = 0.f, s1 = 0.f;
#pragma unroll
    for (int k = 0; k < 16; k += 2) {
      s0 = fmaf(sr[k], we[k], s0);
      s1 = fmaf(sr[k + 1], we[k + 1], s1);
    }
    float deg = (float)(cnt[n] + 1);
    y[(size_t)n * HH + lane] = __float2bfloat16((a0 + a1) + (a2 + a3));
    z[(size_t)n * HH + lane] = __float2bfloat16(
        deg * (((c0 + c1) + (c2 + c3)) + bv) + ((s0 + s1) + wesum));
  }
}

// ---- per-layer gather: wave-per-node, register accumulate, 8-deep ILP ----
// x_new[n] = relu(bn(relu(z[n] + y[n] + sum_{e:dst=n} y[src_e])))  (bf16 out)
#define GTB 25000  // 4 waves/block, wave-per-node; 25000 = 8 * 3125
__global__ __launch_bounds__(256) void k_gath3(
    const __hip_bfloat16* __restrict__ y, const __hip_bfloat16* __restrict__ z,
    const unsigned* __restrict__ ebuf2, const int* __restrict__ rowptr,
    const float* __restrict__ gamma, const float* __restrict__ beta,
    __hip_bfloat16* __restrict__ xn, float* __restrict__ emb) {
  int lane = threadIdx.x & 63;
  int orig = blockIdx.x;
  int blk = (orig & 7) * (GTB / 8) + (orig >> 3);  // XCD-contiguous mapping
  int n0 = blk * 4 + (threadIdx.x >> 6);
  if (n0 >= NN) return;
  int n = __builtin_amdgcn_readfirstlane(n0);
  int lo = rowptr[n], hi = rowptr[n + 1];
  int deg = hi - lo;
  int gb = (n / NPG) * NPG;  // graph base node
  const unsigned* cl = ebuf2 + lo;  // wave-uniform
  const __hip_bfloat16* yg = y + (size_t)gb * HH;
  float acc = __bfloat162float(z[(size_t)n * HH + lane]) +
              __bfloat162float(y[(size_t)n * HH + lane]);  // local + self-loop
  int k = 0;
  for (; k + 8 <= deg; k += 8) {
    int s0 = cl[k] & 1023, s1 = cl[k + 1] & 1023;
    int s2 = cl[k + 2] & 1023, s3 = cl[k + 3] & 1023;
    int s4 = cl[k + 4] & 1023, s5 = cl[k + 5] & 1023;
    int s6 = cl[k + 6] & 1023, s7 = cl[k + 7] & 1023;
    float v0 = __bfloat162float(yg[(size_t)s0 * HH + lane]);
    float v1 = __bfloat162float(yg[(size_t)s1 * HH + lane]);
    float v2 = __bfloat162float(yg[(size_t)s2 * HH + lane]);
    float v3 = __bfloat162float(yg[(size_t)s3 * HH + lane]);
    float v4 = __bfloat162float(yg[(size_t)s4 * HH + lane]);
    float v5 = __bfloat162float(yg[(size_t)s5 * HH + lane]);
    float v6 = __bfloat162float(yg[(size_t)s6 * HH + lane]);
    float v7 = __bfloat162float(yg[(size_t)s7 * HH + lane]);
    acc += ((v0 + v1) + (v2 + v3)) + ((v4 + v5) + (v6 + v7));
  }
  for (; k < deg; ++k)
    acc += __bfloat162float(yg[(size_t)(cl[k] & 1023) * HH + lane]);
  acc = fmaxf(acc, 0.f);                            // relu inside MP layer
  acc = gamma[lane] * acc * BN_SCALE + beta[lane];  // eval BN
  acc = fmaxf(acc, 0.f);                            // relu after BN
  xn[(size_t)n * HH + lane] = __float2bfloat16(acc);
  if (n % NPG == 0) emb[(n / NPG) * HH + lane] = acc;  // spec_idx = g*NPG
}

// ---------------- readout: pool + MLP ----------------
__global__ __launch_bounds__(256) void k_final(
    const __hip_bfloat16* __restrict__ xf, const float* __restrict__ emb,
    const float* __restrict__ nbr, const float* __restrict__ fc1w,
    const float* __restrict__ fc1b, const float* __restrict__ fc2w,
    const float* __restrict__ fc2b, float* __restrict__ out) {
  __shared__ float feats[320];
  __shared__ float pool4[4][64];
  __shared__ float r1[256];
  int g = blockIdx.x;
  int t = threadIdx.x;
  int lane = t & 63, w = t >> 6;
  if (t >= 64) {  // fill embs: feats[64..255]
    int j = t - 64;
    feats[64 + j] = emb[((size_t)(j >> 6) * NG + g) * HH + (j & 63)];
  }
  if (t < 64) feats[256 + t] = nbr[(size_t)g * HH + t];  // neighbor
  float acc = 0.f;
  for (int i = w; i < NPG; i += 4)
    acc += __bfloat162float(xf[(size_t)(g * NPG + i) * HH + lane]);
  pool4[w][lane] = acc;
  __syncthreads();
  if (t < 64) feats[t] = pool4[0][t] + pool4[1][t] + pool4[2][t] + pool4[3][t];
  __syncthreads();
  float a = fc1b[t];
  for (int k = 0; k < 320; ++k) a = fmaf(feats[k], fc1w[k * 256 + t], a);
  r1[t] = fmaxf(a, 0.f);
  __syncthreads();
  if (t < 4) {
    float o = fc2b[t];
    for (int k = 0; k < 256; ++k) o = fmaf(r1[k], fc2w[k * 4 + t], o);
    out[g * 4 + t] = o;
  }
}

extern "C" void kernel_launch(void* const* d_in, const int* in_sizes, int n_in,
                              void* d_out, int out_size, void* d_ws, size_t ws_size,
                              hipStream_t stream) {
  const float* x     = (const float*)d_in[0];
  const float* eattr = (const float*)d_in[1];
  const float* nbr   = (const float*)d_in[2];
  const float* W     = (const float*)d_in[3];
  const float* b     = (const float*)d_in[4];
  const float* gamma = (const float*)d_in[5];
  const float* beta  = (const float*)d_in[6];
  const float* fc1w  = (const float*)d_in[7];
  const float* fc1b  = (const float*)d_in[8];
  const float* fc2w  = (const float*)d_in[9];
  const float* fc2b  = (const float*)d_in[10];
  const int*   ei    = (const int*)d_in[11];
  float* out = (float*)d_out;
  (void)in_sizes; (void)n_in; (void)out_size; (void)ws_size;

  char* p = (char*)d_ws;
  size_t off = 0;
  auto alloc = [&](size_t bytes) {
    char* q = p + off;
    off += (bytes + 255) & ~(size_t)255;
    return q;
  };
  int* hist    = (int*)alloc((size_t)NB * NBIN * 4);
  int* partial = (int*)alloc((size_t)NB * NBIN * 4);
  int* gtot    = (int*)alloc((size_t)NBIN * 4);
  int* gbase   = (int*)alloc((size_t)(NBIN + 1) * 4);
  unsigned long long* ebuf = (unsigned long long*)alloc((size_t)NE * 8);
  unsigned* ebuf2 = (unsigned*)alloc((size_t)NE * 4);
  int* rowptr  = (int*)alloc((size_t)(NN + 1) * 4);
  float* Se    = (float*)alloc((size_t)NN * CE * 4);
  int*   cnt   = (int*)alloc((size_t)NN * 4);
  __hip_bfloat16* ybuf = (__hip_bfloat16*)alloc((size_t)NN * HH * 2);
  __hip_bfloat16* zbuf = (__hip_bfloat16*)alloc((size_t)NN * HH * 2);
  __hip_bfloat16* xA   = (__hip_bfloat16*)alloc((size_t)NN * HH * 2);
  __hip_bfloat16* xB   = (__hip_bfloat16*)alloc((size_t)NN * HH * 2);
  float* emb   = (float*)alloc((size_t)3 * NG * HH * 4);

  // CSR build via two-level counting sort (zero global atomics, no memsets)
  k_hist<<<NB, 256, 0, stream>>>(ei, hist);
  k_scan_a<<<NBIN, 256, 0, stream>>>(hist, partial, gtot);
  k_scan_b<<<1, 512, 0, stream>>>(gtot, gbase);
  k_bfill<<<NB, 256, 0, stream>>>(ei, partial, gbase, ebuf);
  k_nsort<<<NBIN, 256, 0, stream>>>(ebuf, gbase, ebuf2, rowptr, cnt);
  k_se3<<<SEB, 256, 0, stream>>>(ebuf2, rowptr, eattr, Se);

  // layer 0: x (f32) -> xA
  k_gemm<float><<<GB, 256, 0, stream>>>(x, W, b, cnt, Se, ybuf, zbuf);
  k_gath3<<<GTB, 256, 0, stream>>>(ybuf, zbuf, ebuf2, rowptr, gamma, beta, xA, emb);
  // layer 1: xA -> xB
  k_gemm<__hip_bfloat16><<<GB, 256, 0, stream>>>(xA, W + 144 * 64, b + 64, cnt, Se,
                                                 ybuf, zbuf);
  k_gath3<<<GTB, 256, 0, stream>>>(ybuf, zbuf, ebuf2, rowptr, gamma + 64, beta + 64,
                                   xB, emb + NG * HH);
  // layer 2: xB -> xA
  k_gemm<__hip_bfloat16><<<GB, 256, 0, stream>>>(xB, W + 2 * 144 * 64, b + 128, cnt,
                                                 Se, ybuf, zbuf);
  k_gath3<<<GTB, 256, 0, stream>>>(ybuf, zbuf, ebuf2, rowptr, gamma + 128, beta + 128,
                                   xA, emb + 2 * NG * HH);

  k_final<<<NG, 256, 0, stream>>>(xA, emb, nbr, fc1w, fc1b, fc2w, fc2b, out);
}

// Round 10
// 362.640 us; speedup vs baseline: 7.0516x; 1.1547x over previous
//
#include <hip/hip_runtime.h>
#include <hip/hip_bf16.h>

#define NN 100000   // nodes
#define NE 1600000  // edges
#define NG 100      // graphs
#define NPG 1000    // nodes per graph
#define CE 16       // edge channels
#define HH 64       // hidden
#define BN_SCALE 0.99999500003749959f  // 1/sqrt(1+1e-5)
#define NB 200          // edge-chunk blocks
#define ECH (NE / NB)   // 8000 edges per chunk
#define NBIN 400        // dst bins: bin = dst/250 (4 bins per graph)
#define NRANGE 12500    // nodes per XCD range

// LESSON (R3): f32 global atomicAdd on gfx950 = near-memory RMW (~35B HBM each).
// LESSON (R5): int global atomics ~40B each -> counting-sort CSR, no atomics.
// LESSON (R6): edge-per-wave-instruction LDS scatter is ~10x slower than
// wave-per-node register accumulation with 8-deep load ILP.
// LESSON (R8): W "register cache" loaded from LDS stays in LDS (VGPR=84);
// use global loads + launch_bounds(,1) to force true VGPR residency.
// LESSON (R9): un-unrolled load+add loops serialize at ~200cy/iter (L2 lat);
// k_final@100 blocks was 73us with ZERO HBM traffic. Always unroll with
// independent accumulators + spread across enough blocks.

// ---- phase 1: per-chunk histogram over 400 dst-bins (LDS atomics only) ----
__global__ __launch_bounds__(256) void k_hist(const int* __restrict__ ei,
                                              int* __restrict__ hist) {
  __shared__ int h[NBIN];
  for (int i = threadIdx.x; i < NBIN; i += 256) h[i] = 0;
  __syncthreads();
  int e0 = blockIdx.x * ECH;
  for (int i = threadIdx.x; i < ECH; i += 256) {
    int d = ei[NE + e0 + i];
    atomicAdd(&h[d / 250], 1);
  }
  __syncthreads();
  for (int i = threadIdx.x; i < NBIN; i += 256) hist[blockIdx.x * NBIN + i] = h[i];
}

// ---- phase 2a: per-bin exclusive scan over the 200 chunk-counts ----
__global__ __launch_bounds__(256) void k_scan_a(const int* __restrict__ hist,
                                                int* __restrict__ partial,
                                                int* __restrict__ gtot) {
  __shared__ int sv[256];
  int bin = blockIdx.x, t = threadIdx.x;
  int v = (t < NB) ? hist[t * NBIN + bin] : 0;
  sv[t] = v;
  __syncthreads();
  for (int o = 1; o < 256; o <<= 1) {
    int a = (t >= o) ? sv[t - o] : 0;
    __syncthreads();
    sv[t] += a;
    __syncthreads();
  }
  if (t < NB) partial[t * NBIN + bin] = sv[t] - v;
  if (t == 255) gtot[bin] = sv[255];
}

// ---- phase 2b: exclusive scan of the 400 bin totals -> segment bases ----
__global__ __launch_bounds__(512) void k_scan_b(const int* __restrict__ gtot,
                                                int* __restrict__ gbase) {
  __shared__ int sv[512];
  int t = threadIdx.x;
  int v = (t < NBIN) ? gtot[t] : 0;
  sv[t] = v;
  __syncthreads();
  for (int o = 1; o < 512; o <<= 1) {
    int a = (t >= o) ? sv[t - o] : 0;
    __syncthreads();
    sv[t] += a;
    __syncthreads();
  }
  if (t < NBIN) gbase[t] = sv[t] - v;
  if (t == 511) gbase[NBIN] = sv[511];
}

// ---- phase 3: scatter edges into bin segments (LDS cursors, 1x 8B store) ----
// ebuf[pos] = eid<<32 | dst_local<<10 | src_local   (locals are within-graph)
__global__ __launch_bounds__(256) void k_bfill(const int* __restrict__ ei,
                                               const int* __restrict__ partial,
                                               const int* __restrict__ gbase,
                                               unsigned long long* __restrict__ ebuf) {
  __shared__ int cur[NBIN];
  int b = blockIdx.x;
  for (int i = threadIdx.x; i < NBIN; i += 256)
    cur[i] = gbase[i] + partial[b * NBIN + i];
  __syncthreads();
  int e0 = b * ECH;
  for (int i = threadIdx.x; i < ECH; i += 256) {
    int e = e0 + i;
    int d = ei[NE + e], s = ei[e];
    int bin = d / 250;
    int gb = (bin >> 2) * 1000;
    unsigned long long pk = (unsigned long long)(unsigned)e << 32 |
                            (unsigned)((d - gb) << 10) | (unsigned)(s - gb);
    int pos = atomicAdd(&cur[bin], 1);
    ebuf[pos] = pk;
  }
}

// ---- phase 4: within-bin counting sort by node -> per-node CSR ----
// ebuf2[pos] = eid<<10 | src_local (u32); rowptr[n]..rowptr[n+1]; cnt = deg
__global__ __launch_bounds__(256) void k_nsort(
    const unsigned long long* __restrict__ ebuf, const int* __restrict__ gbase,
    unsigned* __restrict__ ebuf2, int* __restrict__ rowptr,
    int* __restrict__ cnt) {
  __shared__ int h[250];
  __shared__ int cur[250];
  __shared__ int sv[256];
  int bin = blockIdx.x, t = threadIdx.x;
  int nb = bin * 250, lbase = (bin & 3) * 250;
  int lo = gbase[bin], hi = gbase[bin + 1];
  if (t < 250) h[t] = 0;
  __syncthreads();
  for (int i = lo + t; i < hi; i += 256) {
    int dl = (int)((ebuf[i] >> 10) & 1023);
    atomicAdd(&h[dl - lbase], 1);
  }
  __syncthreads();
  int v = (t < 250) ? h[t] : 0;
  sv[t] = v;
  __syncthreads();
  for (int o = 1; o < 256; o <<= 1) {
    int a = (t >= o) ? sv[t - o] : 0;
    __syncthreads();
    sv[t] += a;
    __syncthreads();
  }
  if (t < 250) {
    int base = lo + sv[t] - v;  // exclusive
    rowptr[nb + t] = base;
    cur[t] = base;
    cnt[nb + t] = v;
  }
  if (bin == NBIN - 1 && t == 0) rowptr[NN] = hi;
  __syncthreads();
  for (int i = lo + t; i < hi; i += 256) {
    unsigned long long u = ebuf[i];
    int dl = (int)((u >> 10) & 1023);
    unsigned pk = (unsigned)(u >> 32) << 10 | (unsigned)(u & 1023);
    int pos = atomicAdd(&cur[dl - lbase], 1);
    ebuf2[pos] = pk;
  }
}

// ---- Se[n][c] = sum_{e:dst=n} ea[e][c]: wave-per-node, 4 slots x 16 ch ----
#define SEB 25000  // 4 waves/block, wave-per-node; 25000 = 8 * 3125
__global__ __launch_bounds__(256) void k_se3(const unsigned* __restrict__ ebuf2,
                                             const int* __restrict__ rowptr,
                                             const float* __restrict__ ea,
                                             float* __restrict__ Se) {
  int lane = threadIdx.x & 63;
  int s = lane >> 4, c = lane & 15;
  int orig = blockIdx.x;
  int blk = (orig & 7) * (SEB / 8) + (orig >> 3);  // XCD-contiguous mapping
  int n0 = blk * 4 + (threadIdx.x >> 6);
  if (n0 >= NN) return;
  int n = __builtin_amdgcn_readfirstlane(n0);
  int lo = rowptr[n], hi = rowptr[n + 1];
  float acc = 0.f;
  for (int k0 = lo; k0 < hi; k0 += 16) {
    int k1 = k0 + s, k2 = k0 + 4 + s, k3 = k0 + 8 + s, k4 = k0 + 12 + s;
    float v1 = 0.f, v2 = 0.f, v3 = 0.f, v4 = 0.f;
    if (k1 < hi) v1 = ea[(size_t)(ebuf2[k1] >> 10) * CE + c];
    if (k2 < hi) v2 = ea[(size_t)(ebuf2[k2] >> 10) * CE + c];
    if (k3 < hi) v3 = ea[(size_t)(ebuf2[k3] >> 10) * CE + c];
    if (k4 < hi) v4 = ea[(size_t)(ebuf2[k4] >> 10) * CE + c];
    acc += (v1 + v2) + (v3 + v4);
  }
  acc += __shfl_xor(acc, 16);
  acc += __shfl_xor(acc, 32);
  if (lane < 16) Se[(size_t)n * CE + lane] = acc;
}

// ---------------- per-layer node GEMM: no LDS, W columns in VGPRs ----------
#define GB 1024  // 128 blocks per XCD range
template <typename T>
__global__ __launch_bounds__(256, 1) void k_gemm(
    const T* __restrict__ x, const float* __restrict__ W,
    const float* __restrict__ b, const int* __restrict__ cnt,
    const float* __restrict__ Se, __hip_bfloat16* __restrict__ y,
    __hip_bfloat16* __restrict__ z) {
  int lane = threadIdx.x & 63;
  float wi[64], wj[64], we[16];
#pragma unroll
  for (int k = 0; k < 64; ++k) wi[k] = W[k * 64 + lane];
#pragma unroll
  for (int k = 0; k < 64; ++k) wj[k] = W[(64 + k) * 64 + lane];
#pragma unroll
  for (int k = 0; k < 16; ++k) we[k] = W[(128 + k) * 64 + lane];
  float bv = b[lane];
  float wesum = 0.f;  // self-loop edge_attr = ones
#pragma unroll
  for (int k = 0; k < 16; ++k) wesum += we[k];
  int xcd = blockIdx.x & 7;
  int wid = (blockIdx.x >> 3) * 4 + (threadIdx.x >> 6);  // 0..511 in range
  int lo = xcd * NRANGE, hi = lo + NRANGE;
  const int stride = (GB / 8) * 4;
  for (int n0 = lo + wid; n0 < hi; n0 += stride) {
    int n = __builtin_amdgcn_readfirstlane(n0);  // wave-uniform -> s_load row
    float xv[64];  // uniform values -> SGPRs
    if constexpr (sizeof(T) == 4) {
      const float* xr = (const float*)x + (size_t)n * HH;
#pragma unroll
      for (int k = 0; k < 64; ++k) xv[k] = xr[k];
    } else {
      const unsigned* xr = (const unsigned*)((const T*)x + (size_t)n * HH);
#pragma unroll
      for (int k2 = 0; k2 < 32; ++k2) {
        unsigned u = xr[k2];
        xv[2 * k2] = __uint_as_float(u << 16);
        xv[2 * k2 + 1] = __uint_as_float(u & 0xffff0000u);
      }
    }
    const float* sr = Se + (size_t)n * CE;
    float a0 = 0.f, a1 = 0.f, a2 = 0.f, a3 = 0.f;
    float c0 = 0.f, c1 = 0.f, c2 = 0.f, c3 = 0.f;
#pragma unroll
    for (int k = 0; k < 64; k += 4) {
      a0 = fmaf(xv[k], wj[k], a0);
      a1 = fmaf(xv[k + 1], wj[k + 1], a1);
      a2 = fmaf(xv[k + 2], wj[k + 2], a2);
      a3 = fmaf(xv[k + 3], wj[k + 3], a3);
      c0 = fmaf(xv[k], wi[k], c0);
      c1 = fmaf(xv[k + 1], wi[k + 1], c1);
      c2 = fmaf(xv[k + 2], wi[k + 2], c2);
      c3 = fmaf(xv[k + 3], wi[k + 3], c3);
    }
    float s0 = 0.f, s1 = 0.f;
#pragma unroll
    for (int k = 0; k < 16; k += 2) {
      s0 = fmaf(sr[k], we[k], s0);
      s1 = fmaf(sr[k + 1], we[k + 1], s1);
    }
    float deg = (float)(cnt[n] + 1);
    y[(size_t)n * HH + lane] = __float2bfloat16((a0 + a1) + (a2 + a3));
    z[(size_t)n * HH + lane] = __float2bfloat16(
        deg * (((c0 + c1) + (c2 + c3)) + bv) + ((s0 + s1) + wesum));
  }
}

// ---- per-layer gather: wave-per-node, register accumulate, 8-deep ILP ----
#define GTB 25000  // 4 waves/block, wave-per-node; 25000 = 8 * 3125
__global__ __launch_bounds__(256) void k_gath3(
    const __hip_bfloat16* __restrict__ y, const __hip_bfloat16* __restrict__ z,
    const unsigned* __restrict__ ebuf2, const int* __restrict__ rowptr,
    const float* __restrict__ gamma, const float* __restrict__ beta,
    __hip_bfloat16* __restrict__ xn, float* __restrict__ emb) {
  int lane = threadIdx.x & 63;
  int orig = blockIdx.x;
  int blk = (orig & 7) * (GTB / 8) + (orig >> 3);  // XCD-contiguous mapping
  int n0 = blk * 4 + (threadIdx.x >> 6);
  if (n0 >= NN) return;
  int n = __builtin_amdgcn_readfirstlane(n0);
  int lo = rowptr[n], hi = rowptr[n + 1];
  int deg = hi - lo;
  int gb = (n / NPG) * NPG;  // graph base node
  const unsigned* cl = ebuf2 + lo;  // wave-uniform
  const __hip_bfloat16* yg = y + (size_t)gb * HH;
  float acc = __bfloat162float(z[(size_t)n * HH + lane]) +
              __bfloat162float(y[(size_t)n * HH + lane]);  // local + self-loop
  int k = 0;
  for (; k + 8 <= deg; k += 8) {
    int s0 = cl[k] & 1023, s1 = cl[k + 1] & 1023;
    int s2 = cl[k + 2] & 1023, s3 = cl[k + 3] & 1023;
    int s4 = cl[k + 4] & 1023, s5 = cl[k + 5] & 1023;
    int s6 = cl[k + 6] & 1023, s7 = cl[k + 7] & 1023;
    float v0 = __bfloat162float(yg[(size_t)s0 * HH + lane]);
    float v1 = __bfloat162float(yg[(size_t)s1 * HH + lane]);
    float v2 = __bfloat162float(yg[(size_t)s2 * HH + lane]);
    float v3 = __bfloat162float(yg[(size_t)s3 * HH + lane]);
    float v4 = __bfloat162float(yg[(size_t)s4 * HH + lane]);
    float v5 = __bfloat162float(yg[(size_t)s5 * HH + lane]);
    float v6 = __bfloat162float(yg[(size_t)s6 * HH + lane]);
    float v7 = __bfloat162float(yg[(size_t)s7 * HH + lane]);
    acc += ((v0 + v1) + (v2 + v3)) + ((v4 + v5) + (v6 + v7));
  }
  for (; k < deg; ++k)
    acc += __bfloat162float(yg[(size_t)(cl[k] & 1023) * HH + lane]);
  acc = fmaxf(acc, 0.f);                            // relu inside MP layer
  acc = gamma[lane] * acc * BN_SCALE + beta[lane];  // eval BN
  acc = fmaxf(acc, 0.f);                            // relu after BN
  xn[(size_t)n * HH + lane] = __float2bfloat16(acc);
  if (n % NPG == 0) emb[(n / NPG) * HH + lane] = acc;  // spec_idx = g*NPG
}

// ---- pool: 400 blocks x 8 waves, 4-deep unrolled; partial[bin][64] f32 ----
__global__ __launch_bounds__(512) void k_pool(const __hip_bfloat16* __restrict__ xf,
                                              float* __restrict__ partial) {
  __shared__ float pp[8][64];
  int bin = blockIdx.x;
  int lane = threadIdx.x & 63, wv = threadIdx.x >> 6;
  const __hip_bfloat16* base = xf + (size_t)bin * 250 * HH;
  float acc = 0.f;
  int i = wv;
  for (; i + 24 < 250; i += 32) {
    float v0 = __bfloat162float(base[(size_t)i * HH + lane]);
    float v1 = __bfloat162float(base[(size_t)(i + 8) * HH + lane]);
    float v2 = __bfloat162float(base[(size_t)(i + 16) * HH + lane]);
    float v3 = __bfloat162float(base[(size_t)(i + 24) * HH + lane]);
    acc += (v0 + v1) + (v2 + v3);
  }
  for (; i < 250; i += 8) acc += __bfloat162float(base[(size_t)i * HH + lane]);
  pp[wv][lane] = acc;
  __syncthreads();
  if (wv == 0) {
    float s = ((pp[0][lane] + pp[1][lane]) + (pp[2][lane] + pp[3][lane])) +
              ((pp[4][lane] + pp[5][lane]) + (pp[6][lane] + pp[7][lane]));
    partial[bin * 64 + lane] = s;
  }
}

// ---------------- readout MLP: ILP-unrolled fc1, parallel fc2 ----------------
__global__ __launch_bounds__(256) void k_final(
    const float* __restrict__ partial, const float* __restrict__ emb,
    const float* __restrict__ nbr, const float* __restrict__ fc1w,
    const float* __restrict__ fc1b, const float* __restrict__ fc2w,
    const float* __restrict__ fc2b, float* __restrict__ out) {
  __shared__ float feats[320];
  __shared__ float r1[256];
  __shared__ float red[4][4];
  int g = blockIdx.x;
  int t = threadIdx.x;
  if (t < 64) {
    const float* pb = partial + 4 * g * 64;
    feats[t] = (pb[t] + pb[64 + t]) + (pb[128 + t] + pb[192 + t]);
    feats[256 + t] = nbr[(size_t)g * HH + t];
  } else {
    int j = t - 64;  // 0..191 -> 3 layer embs
    feats[64 + j] = emb[((size_t)(j >> 6) * NG + g) * HH + (j & 63)];
  }
  __syncthreads();
  float a0 = fc1b[t], a1 = 0.f, a2 = 0.f, a3 = 0.f;
  const float* wp = fc1w + t;
  for (int k = 0; k < 320; k += 8) {  // 8 loads in flight, 4 accumulators
    float w0 = wp[(k + 0) * 256], w1 = wp[(k + 1) * 256];
    float w2 = wp[(k + 2) * 256], w3 = wp[(k + 3) * 256];
    float w4 = wp[(k + 4) * 256], w5 = wp[(k + 5) * 256];
    float w6 = wp[(k + 6) * 256], w7 = wp[(k + 7) * 256];
    a0 = fmaf(feats[k], w0, a0);
    a1 = fmaf(feats[k + 1], w1, a1);
    a2 = fmaf(feats[k + 2], w2, a2);
    a3 = fmaf(feats[k + 3], w3, a3);
    a0 = fmaf(feats[k + 4], w4, a0);
    a1 = fmaf(feats[k + 5], w5, a1);
    a2 = fmaf(feats[k + 6], w6, a2);
    a3 = fmaf(feats[k + 7], w7, a3);
  }
  float rv = fmaxf((a0 + a1) + (a2 + a3), 0.f);
  r1[t] = rv;
  // fc2 parallel: each thread's 4 products, wave-reduce, cross-wave combine
  float p0 = rv * fc2w[t * 4 + 0];
  float p1 = rv * fc2w[t * 4 + 1];
  float p2 = rv * fc2w[t * 4 + 2];
  float p3 = rv * fc2w[t * 4 + 3];
#pragma unroll
  for (int o = 1; o < 64; o <<= 1) {
    p0 += __shfl_xor(p0, o);
    p1 += __shfl_xor(p1, o);
    p2 += __shfl_xor(p2, o);
    p3 += __shfl_xor(p3, o);
  }
  if ((t & 63) == 0) {
    int wv = t >> 6;
    red[wv][0] = p0; red[wv][1] = p1; red[wv][2] = p2; red[wv][3] = p3;
  }
  __syncthreads();
  if (t < 4)
    out[g * 4 + t] = fc2b[t] +
                     ((red[0][t] + red[1][t]) + (red[2][t] + red[3][t]));
}

extern "C" void kernel_launch(void* const* d_in, const int* in_sizes, int n_in,
                              void* d_out, int out_size, void* d_ws, size_t ws_size,
                              hipStream_t stream) {
  const float* x     = (const float*)d_in[0];
  const float* eattr = (const float*)d_in[1];
  const float* nbr   = (const float*)d_in[2];
  const float* W     = (const float*)d_in[3];
  const float* b     = (const float*)d_in[4];
  const float* gamma = (const float*)d_in[5];
  const float* beta  = (const float*)d_in[6];
  const float* fc1w  = (const float*)d_in[7];
  const float* fc1b  = (const float*)d_in[8];
  const float* fc2w  = (const float*)d_in[9];
  const float* fc2b  = (const float*)d_in[10];
  const int*   ei    = (const int*)d_in[11];
  float* out = (float*)d_out;
  (void)in_sizes; (void)n_in; (void)out_size; (void)ws_size;

  char* p = (char*)d_ws;
  size_t off = 0;
  auto alloc = [&](size_t bytes) {
    char* q = p + off;
    off += (bytes + 255) & ~(size_t)255;
    return q;
  };
  int* hist    = (int*)alloc((size_t)NB * NBIN * 4);
  int* partial = (int*)alloc((size_t)NB * NBIN * 4);
  int* gtot    = (int*)alloc((size_t)NBIN * 4);
  int* gbase   = (int*)alloc((size_t)(NBIN + 1) * 4);
  unsigned long long* ebuf = (unsigned long long*)alloc((size_t)NE * 8);
  unsigned* ebuf2 = (unsigned*)alloc((size_t)NE * 4);
  int* rowptr  = (int*)alloc((size_t)(NN + 1) * 4);
  float* Se    = (float*)alloc((size_t)NN * CE * 4);
  int*   cnt   = (int*)alloc((size_t)NN * 4);
  __hip_bfloat16* ybuf = (__hip_bfloat16*)alloc((size_t)NN * HH * 2);
  __hip_bfloat16* zbuf = (__hip_bfloat16*)alloc((size_t)NN * HH * 2);
  __hip_bfloat16* xA   = (__hip_bfloat16*)alloc((size_t)NN * HH * 2);
  __hip_bfloat16* xB   = (__hip_bfloat16*)alloc((size_t)NN * HH * 2);
  float* emb   = (float*)alloc((size_t)3 * NG * HH * 4);
  float* pool  = (float*)alloc((size_t)NBIN * HH * 4);

  // CSR build via two-level counting sort (zero global atomics, no memsets)
  k_hist<<<NB, 256, 0, stream>>>(ei, hist);
  k_scan_a<<<NBIN, 256, 0, stream>>>(hist, partial, gtot);
  k_scan_b<<<1, 512, 0, stream>>>(gtot, gbase);
  k_bfill<<<NB, 256, 0, stream>>>(ei, partial, gbase, ebuf);
  k_nsort<<<NBIN, 256, 0, stream>>>(ebuf, gbase, ebuf2, rowptr, cnt);
  k_se3<<<SEB, 256, 0, stream>>>(ebuf2, rowptr, eattr, Se);

  // layer 0: x (f32) -> xA
  k_gemm<float><<<GB, 256, 0, stream>>>(x, W, b, cnt, Se, ybuf, zbuf);
  k_gath3<<<GTB, 256, 0, stream>>>(ybuf, zbuf, ebuf2, rowptr, gamma, beta, xA, emb);
  // layer 1: xA -> xB
  k_gemm<__hip_bfloat16><<<GB, 256, 0, stream>>>(xA, W + 144 * 64, b + 64, cnt, Se,
                                                 ybuf, zbuf);
  k_gath3<<<GTB, 256, 0, stream>>>(ybuf, zbuf, ebuf2, rowptr, gamma + 64, beta + 64,
                                   xB, emb + NG * HH);
  // layer 2: xB -> xA
  k_gemm<__hip_bfloat16><<<GB, 256, 0, stream>>>(xB, W + 2 * 144 * 64, b + 128, cnt,
                                                 Se, ybuf, zbuf);
  k_gath3<<<GTB, 256, 0, stream>>>(ybuf, zbuf, ebuf2, rowptr, gamma + 128, beta + 128,
                                   xA, emb + 2 * NG * HH);

  k_pool<<<NBIN, 512, 0, stream>>>(xA, pool);
  k_final<<<NG, 256, 0, stream>>>(pool, emb, nbr, fc1w, fc1b, fc2w, fc2b, out);
}

// Round 11
// 356.110 us; speedup vs baseline: 7.1810x; 1.0183x over previous
//
#include <hip/hip_runtime.h>
#include <hip/hip_bf16.h>

#define NN 100000   // nodes
#define NE 1600000  // edges
#define NG 100      // graphs
#define NPG 1000    // nodes per graph
#define CE 16       // edge channels
#define HH 64       // hidden
#define BN_SCALE 0.99999500003749959f  // 1/sqrt(1+1e-5)
#define NB 200          // edge-chunk blocks
#define ECH (NE / NB)   // 8000 edges per chunk
#define NBIN 400        // dst bins: bin = dst/250 (4 bins per graph)
#define NRANGE 12500    // nodes per XCD range

// LESSON (R3): f32 global atomicAdd on gfx950 = near-memory RMW (~35B HBM each).
// LESSON (R5): int global atomics ~40B each -> counting-sort CSR, no atomics.
// LESSON (R6): edge-per-wave-instruction LDS scatter is ~10x slower than
// wave-per-node register accumulation with 8-deep load ILP.
// LESSON (R8): W "register cache" loaded from LDS stays in LDS (VGPR=84);
// use global loads + launch_bounds(,1) to force true VGPR residency.
// LESSON (R9): un-unrolled load+add loops serialize at L2/L3 latency.
// LESSON (R10): guarded loads (`if (k<hi) v=load`) compile to branch blocks
// that SERIALIZE the "independent" loads (VGPR=8 tell); replay-invariant time
// with L3-resident data = latency-bound. Use clamp+cndmask so loads always
// issue, and widen to float4 so each wave-instruction covers 16 rows.

// ---- phase 1: per-chunk histogram over 400 dst-bins (LDS atomics only) ----
__global__ __launch_bounds__(256) void k_hist(const int* __restrict__ ei,
                                              int* __restrict__ hist) {
  __shared__ int h[NBIN];
  for (int i = threadIdx.x; i < NBIN; i += 256) h[i] = 0;
  __syncthreads();
  int e0 = blockIdx.x * ECH;
  for (int i = threadIdx.x; i < ECH; i += 256) {
    int d = ei[NE + e0 + i];
    atomicAdd(&h[d / 250], 1);
  }
  __syncthreads();
  for (int i = threadIdx.x; i < NBIN; i += 256) hist[blockIdx.x * NBIN + i] = h[i];
}

// ---- phase 2a: per-bin exclusive scan over the 200 chunk-counts ----
__global__ __launch_bounds__(256) void k_scan_a(const int* __restrict__ hist,
                                                int* __restrict__ partial,
                                                int* __restrict__ gtot) {
  __shared__ int sv[256];
  int bin = blockIdx.x, t = threadIdx.x;
  int v = (t < NB) ? hist[t * NBIN + bin] : 0;
  sv[t] = v;
  __syncthreads();
  for (int o = 1; o < 256; o <<= 1) {
    int a = (t >= o) ? sv[t - o] : 0;
    __syncthreads();
    sv[t] += a;
    __syncthreads();
  }
  if (t < NB) partial[t * NBIN + bin] = sv[t] - v;
  if (t == 255) gtot[bin] = sv[255];
}

// ---- phase 2b: exclusive scan of the 400 bin totals -> segment bases ----
__global__ __launch_bounds__(512) void k_scan_b(const int* __restrict__ gtot,
                                                int* __restrict__ gbase) {
  __shared__ int sv[512];
  int t = threadIdx.x;
  int v = (t < NBIN) ? gtot[t] : 0;
  sv[t] = v;
  __syncthreads();
  for (int o = 1; o < 512; o <<= 1) {
    int a = (t >= o) ? sv[t - o] : 0;
    __syncthreads();
    sv[t] += a;
    __syncthreads();
  }
  if (t < NBIN) gbase[t] = sv[t] - v;
  if (t == 511) gbase[NBIN] = sv[511];
}

// ---- phase 3: scatter edges into bin segments (LDS cursors, 1x 8B store) ----
// ebuf[pos] = eid<<32 | dst_local<<10 | src_local   (locals are within-graph)
__global__ __launch_bounds__(256) void k_bfill(const int* __restrict__ ei,
                                               const int* __restrict__ partial,
                                               const int* __restrict__ gbase,
                                               unsigned long long* __restrict__ ebuf) {
  __shared__ int cur[NBIN];
  int b = blockIdx.x;
  for (int i = threadIdx.x; i < NBIN; i += 256)
    cur[i] = gbase[i] + partial[b * NBIN + i];
  __syncthreads();
  int e0 = b * ECH;
  for (int i = threadIdx.x; i < ECH; i += 256) {
    int e = e0 + i;
    int d = ei[NE + e], s = ei[e];
    int bin = d / 250;
    int gb = (bin >> 2) * 1000;
    unsigned long long pk = (unsigned long long)(unsigned)e << 32 |
                            (unsigned)((d - gb) << 10) | (unsigned)(s - gb);
    int pos = atomicAdd(&cur[bin], 1);
    ebuf[pos] = pk;
  }
}

// ---- phase 4: within-bin counting sort by node -> per-node CSR ----
// ebuf2[pos] = eid<<10 | src_local (u32); rowptr[n]..rowptr[n+1]; cnt = deg
__global__ __launch_bounds__(256) void k_nsort(
    const unsigned long long* __restrict__ ebuf, const int* __restrict__ gbase,
    unsigned* __restrict__ ebuf2, int* __restrict__ rowptr,
    int* __restrict__ cnt) {
  __shared__ int h[250];
  __shared__ int cur[250];
  __shared__ int sv[256];
  int bin = blockIdx.x, t = threadIdx.x;
  int nb = bin * 250, lbase = (bin & 3) * 250;
  int lo = gbase[bin], hi = gbase[bin + 1];
  if (t < 250) h[t] = 0;
  __syncthreads();
  for (int i = lo + t; i < hi; i += 256) {
    int dl = (int)((ebuf[i] >> 10) & 1023);
    atomicAdd(&h[dl - lbase], 1);
  }
  __syncthreads();
  int v = (t < 250) ? h[t] : 0;
  sv[t] = v;
  __syncthreads();
  for (int o = 1; o < 256; o <<= 1) {
    int a = (t >= o) ? sv[t - o] : 0;
    __syncthreads();
    sv[t] += a;
    __syncthreads();
  }
  if (t < 250) {
    int base = lo + sv[t] - v;  // exclusive
    rowptr[nb + t] = base;
    cur[t] = base;
    cnt[nb + t] = v;
  }
  if (bin == NBIN - 1 && t == 0) rowptr[NN] = hi;
  __syncthreads();
  for (int i = lo + t; i < hi; i += 256) {
    unsigned long long u = ebuf[i];
    int dl = (int)((u >> 10) & 1023);
    unsigned pk = (unsigned)(u >> 32) << 10 | (unsigned)(u & 1023);
    int pos = atomicAdd(&cur[dl - lbase], 1);
    ebuf2[pos] = pk;
  }
}

// ---- Se[n][c]: wave-per-node, lane = slot(16) x quarter(4), float4 loads ----
// 32 edge-rows in flight per wave (2 unguarded dwordx4 loads/lane, cndmask
// zeroing). Cross-slot reduce via 4x shfl_xor on 4 floats.
#define SEB 25000  // 4 waves/block, wave-per-node; 25000 = 8 * 3125
__global__ __launch_bounds__(256) void k_se3(const unsigned* __restrict__ ebuf2,
                                             const int* __restrict__ rowptr,
                                             const float* __restrict__ ea,
                                             float* __restrict__ Se) {
  int lane = threadIdx.x & 63;
  int slot = lane >> 2;  // edge slot 0..15
  int q = lane & 3;      // row quarter (4 channels)
  int orig = blockIdx.x;
  int blk = (orig & 7) * (SEB / 8) + (orig >> 3);  // XCD-contiguous mapping
  int n0 = blk * 4 + (threadIdx.x >> 6);
  if (n0 >= NN) return;
  int n = __builtin_amdgcn_readfirstlane(n0);
  int lo = rowptr[n], hi = rowptr[n + 1];
  float aA0 = 0.f, aA1 = 0.f, aA2 = 0.f, aA3 = 0.f;
  float aB0 = 0.f, aB1 = 0.f, aB2 = 0.f, aB3 = 0.f;
  for (int k0 = lo; k0 < hi; k0 += 32) {
    int ka = k0 + slot, kb = k0 + 16 + slot;
    int kca = min(ka, NE - 1), kcb = min(kb, NE - 1);
    unsigned eida = ebuf2[kca] >> 10;
    unsigned eidb = ebuf2[kcb] >> 10;
    float4 va = *(const float4*)(ea + (size_t)eida * CE + q * 4);
    float4 vb = *(const float4*)(ea + (size_t)eidb * CE + q * 4);
    bool oka = ka < hi, okb = kb < hi;
    aA0 += oka ? va.x : 0.f;
    aA1 += oka ? va.y : 0.f;
    aA2 += oka ? va.z : 0.f;
    aA3 += oka ? va.w : 0.f;
    aB0 += okb ? vb.x : 0.f;
    aB1 += okb ? vb.y : 0.f;
    aB2 += okb ? vb.z : 0.f;
    aB3 += okb ? vb.w : 0.f;
  }
  float r0 = aA0 + aB0, r1 = aA1 + aB1, r2 = aA2 + aB2, r3 = aA3 + aB3;
#pragma unroll
  for (int o = 4; o < 64; o <<= 1) {  // reduce across the 16 slots
    r0 += __shfl_xor(r0, o);
    r1 += __shfl_xor(r1, o);
    r2 += __shfl_xor(r2, o);
    r3 += __shfl_xor(r3, o);
  }
  if (lane < 4) {  // lane==q holds channels q*4..q*4+3
    float4 w = make_float4(r0, r1, r2, r3);
    *(float4*)(Se + (size_t)n * CE + lane * 4) = w;
  }
}

// ---------------- per-layer node GEMM: no LDS, W columns in VGPRs ----------
#define GB 1024  // 128 blocks per XCD range
template <typename T>
__global__ __launch_bounds__(256, 1) void k_gemm(
    const T* __restrict__ x, const float* __restrict__ W,
    const float* __restrict__ b, const int* __restrict__ cnt,
    const float* __restrict__ Se, __hip_bfloat16* __restrict__ y,
    __hip_bfloat16* __restrict__ z) {
  int lane = threadIdx.x & 63;
  float wi[64], wj[64], we[16];
#pragma unroll
  for (int k = 0; k < 64; ++k) wi[k] = W[k * 64 + lane];
#pragma unroll
  for (int k = 0; k < 64; ++k) wj[k] = W[(64 + k) * 64 + lane];
#pragma unroll
  for (int k = 0; k < 16; ++k) we[k] = W[(128 + k) * 64 + lane];
  float bv = b[lane];
  float wesum = 0.f;  // self-loop edge_attr = ones
#pragma unroll
  for (int k = 0; k < 16; ++k) wesum += we[k];
  int xcd = blockIdx.x & 7;
  int wid = (blockIdx.x >> 3) * 4 + (threadIdx.x >> 6);  // 0..511 in range
  int lo = xcd * NRANGE, hi = lo + NRANGE;
  const int stride = (GB / 8) * 4;
  for (int n0 = lo + wid; n0 < hi; n0 += stride) {
    int n = __builtin_amdgcn_readfirstlane(n0);  // wave-uniform -> s_load row
    float xv[64];  // uniform values -> SGPRs
    if constexpr (sizeof(T) == 4) {
      const float* xr = (const float*)x + (size_t)n * HH;
#pragma unroll
      for (int k = 0; k < 64; ++k) xv[k] = xr[k];
    } else {
      const unsigned* xr = (const unsigned*)((const T*)x + (size_t)n * HH);
#pragma unroll
      for (int k2 = 0; k2 < 32; ++k2) {
        unsigned u = xr[k2];
        xv[2 * k2] = __uint_as_float(u << 16);
        xv[2 * k2 + 1] = __uint_as_float(u & 0xffff0000u);
      }
    }
    const float* sr = Se + (size_t)n * CE;
    float a0 = 0.f, a1 = 0.f, a2 = 0.f, a3 = 0.f;
    float c0 = 0.f, c1 = 0.f, c2 = 0.f, c3 = 0.f;
#pragma unroll
    for (int k = 0; k < 64; k += 4) {
      a0 = fmaf(xv[k], wj[k], a0);
      a1 = fmaf(xv[k + 1], wj[k + 1], a1);
      a2 = fmaf(xv[k + 2], wj[k + 2], a2);
      a3 = fmaf(xv[k + 3], wj[k + 3], a3);
      c0 = fmaf(xv[k], wi[k], c0);
      c1 = fmaf(xv[k + 1], wi[k + 1], c1);
      c2 = fmaf(xv[k + 2], wi[k + 2], c2);
      c3 = fmaf(xv[k + 3], wi[k + 3], c3);
    }
    float s0 = 0.f, s1 = 0.f;
#pragma unroll
    for (int k = 0; k < 16; k += 2) {
      s0 = fmaf(sr[k], we[k], s0);
      s1 = fmaf(sr[k + 1], we[k + 1], s1);
    }
    float deg = (float)(cnt[n] + 1);
    y[(size_t)n * HH + lane] = __float2bfloat16((a0 + a1) + (a2 + a3));
    z[(size_t)n * HH + lane] = __float2bfloat16(
        deg * (((c0 + c1) + (c2 + c3)) + bv) + ((s0 + s1) + wesum));
  }
}

// ---- per-layer gather: wave-per-node, register accumulate, 8-deep ILP ----
#define GTB 25000  // 4 waves/block, wave-per-node; 25000 = 8 * 3125
__global__ __launch_bounds__(256) void k_gath3(
    const __hip_bfloat16* __restrict__ y, const __hip_bfloat16* __restrict__ z,
    const unsigned* __restrict__ ebuf2, const int* __restrict__ rowptr,
    const float* __restrict__ gamma, const float* __restrict__ beta,
    __hip_bfloat16* __restrict__ xn, float* __restrict__ emb) {
  int lane = threadIdx.x & 63;
  int orig = blockIdx.x;
  int blk = (orig & 7) * (GTB / 8) + (orig >> 3);  // XCD-contiguous mapping
  int n0 = blk * 4 + (threadIdx.x >> 6);
  if (n0 >= NN) return;
  int n = __builtin_amdgcn_readfirstlane(n0);
  int lo = rowptr[n], hi = rowptr[n + 1];
  int deg = hi - lo;
  int gb = (n / NPG) * NPG;  // graph base node
  const unsigned* cl = ebuf2 + lo;  // wave-uniform
  const __hip_bfloat16* yg = y + (size_t)gb * HH;
  float acc = __bfloat162float(z[(size_t)n * HH + lane]) +
              __bfloat162float(y[(size_t)n * HH + lane]);  // local + self-loop
  int k = 0;
  for (; k + 8 <= deg; k += 8) {
    int s0 = cl[k] & 1023, s1 = cl[k + 1] & 1023;
    int s2 = cl[k + 2] & 1023, s3 = cl[k + 3] & 1023;
    int s4 = cl[k + 4] & 1023, s5 = cl[k + 5] & 1023;
    int s6 = cl[k + 6] & 1023, s7 = cl[k + 7] & 1023;
    float v0 = __bfloat162float(yg[(size_t)s0 * HH + lane]);
    float v1 = __bfloat162float(yg[(size_t)s1 * HH + lane]);
    float v2 = __bfloat162float(yg[(size_t)s2 * HH + lane]);
    float v3 = __bfloat162float(yg[(size_t)s3 * HH + lane]);
    float v4 = __bfloat162float(yg[(size_t)s4 * HH + lane]);
    float v5 = __bfloat162float(yg[(size_t)s5 * HH + lane]);
    float v6 = __bfloat162float(yg[(size_t)s6 * HH + lane]);
    float v7 = __bfloat162float(yg[(size_t)s7 * HH + lane]);
    acc += ((v0 + v1) + (v2 + v3)) + ((v4 + v5) + (v6 + v7));
  }
  for (; k < deg; ++k)
    acc += __bfloat162float(yg[(size_t)(cl[k] & 1023) * HH + lane]);
  acc = fmaxf(acc, 0.f);                            // relu inside MP layer
  acc = gamma[lane] * acc * BN_SCALE + beta[lane];  // eval BN
  acc = fmaxf(acc, 0.f);                            // relu after BN
  xn[(size_t)n * HH + lane] = __float2bfloat16(acc);
  if (n % NPG == 0) emb[(n / NPG) * HH + lane] = acc;  // spec_idx = g*NPG
}

// ---- pool: 400 blocks x 8 waves, 4-deep unrolled; partial[bin][64] f32 ----
__global__ __launch_bounds__(512) void k_pool(const __hip_bfloat16* __restrict__ xf,
                                              float* __restrict__ partial) {
  __shared__ float pp[8][64];
  int bin = blockIdx.x;
  int lane = threadIdx.x & 63, wv = threadIdx.x >> 6;
  const __hip_bfloat16* base = xf + (size_t)bin * 250 * HH;
  float acc = 0.f;
  int i = wv;
  for (; i + 24 < 250; i += 32) {
    float v0 = __bfloat162float(base[(size_t)i * HH + lane]);
    float v1 = __bfloat162float(base[(size_t)(i + 8) * HH + lane]);
    float v2 = __bfloat162float(base[(size_t)(i + 16) * HH + lane]);
    float v3 = __bfloat162float(base[(size_t)(i + 24) * HH + lane]);
    acc += (v0 + v1) + (v2 + v3);
  }
  for (; i < 250; i += 8) acc += __bfloat162float(base[(size_t)i * HH + lane]);
  pp[wv][lane] = acc;
  __syncthreads();
  if (wv == 0) {
    float s = ((pp[0][lane] + pp[1][lane]) + (pp[2][lane] + pp[3][lane])) +
              ((pp[4][lane] + pp[5][lane]) + (pp[6][lane] + pp[7][lane]));
    partial[bin * 64 + lane] = s;
  }
}

// ---------------- readout MLP: ILP-unrolled fc1, parallel fc2 ----------------
__global__ __launch_bounds__(256) void k_final(
    const float* __restrict__ partial, const float* __restrict__ emb,
    const float* __restrict__ nbr, const float* __restrict__ fc1w,
    const float* __restrict__ fc1b, const float* __restrict__ fc2w,
    const float* __restrict__ fc2b, float* __restrict__ out) {
  __shared__ float feats[320];
  __shared__ float r1[256];
  __shared__ float red[4][4];
  int g = blockIdx.x;
  int t = threadIdx.x;
  if (t < 64) {
    const float* pb = partial + 4 * g * 64;
    feats[t] = (pb[t] + pb[64 + t]) + (pb[128 + t] + pb[192 + t]);
    feats[256 + t] = nbr[(size_t)g * HH + t];
  } else {
    int j = t - 64;  // 0..191 -> 3 layer embs
    feats[64 + j] = emb[((size_t)(j >> 6) * NG + g) * HH + (j & 63)];
  }
  __syncthreads();
  float a0 = fc1b[t], a1 = 0.f, a2 = 0.f, a3 = 0.f;
  const float* wp = fc1w + t;
  for (int k = 0; k < 320; k += 8) {  // 8 loads in flight, 4 accumulators
    float w0 = wp[(k + 0) * 256], w1 = wp[(k + 1) * 256];
    float w2 = wp[(k + 2) * 256], w3 = wp[(k + 3) * 256];
    float w4 = wp[(k + 4) * 256], w5 = wp[(k + 5) * 256];
    float w6 = wp[(k + 6) * 256], w7 = wp[(k + 7) * 256];
    a0 = fmaf(feats[k], w0, a0);
    a1 = fmaf(feats[k + 1], w1, a1);
    a2 = fmaf(feats[k + 2], w2, a2);
    a3 = fmaf(feats[k + 3], w3, a3);
    a0 = fmaf(feats[k + 4], w4, a0);
    a1 = fmaf(feats[k + 5], w5, a1);
    a2 = fmaf(feats[k + 6], w6, a2);
    a3 = fmaf(feats[k + 7], w7, a3);
  }
  float rv = fmaxf((a0 + a1) + (a2 + a3), 0.f);
  r1[t] = rv;
  // fc2 parallel: each thread's 4 products, wave-reduce, cross-wave combine
  float p0 = rv * fc2w[t * 4 + 0];
  float p1 = rv * fc2w[t * 4 + 1];
  float p2 = rv * fc2w[t * 4 + 2];
  float p3 = rv * fc2w[t * 4 + 3];
#pragma unroll
  for (int o = 1; o < 64; o <<= 1) {
    p0 += __shfl_xor(p0, o);
    p1 += __shfl_xor(p1, o);
    p2 += __shfl_xor(p2, o);
    p3 += __shfl_xor(p3, o);
  }
  if ((t & 63) == 0) {
    int wv = t >> 6;
    red[wv][0] = p0; red[wv][1] = p1; red[wv][2] = p2; red[wv][3] = p3;
  }
  __syncthreads();
  if (t < 4)
    out[g * 4 + t] = fc2b[t] +
                     ((red[0][t] + red[1][t]) + (red[2][t] + red[3][t]));
}

extern "C" void kernel_launch(void* const* d_in, const int* in_sizes, int n_in,
                              void* d_out, int out_size, void* d_ws, size_t ws_size,
                              hipStream_t stream) {
  const float* x     = (const float*)d_in[0];
  const float* eattr = (const float*)d_in[1];
  const float* nbr   = (const float*)d_in[2];
  const float* W     = (const float*)d_in[3];
  const float* b     = (const float*)d_in[4];
  const float* gamma = (const float*)d_in[5];
  const float* beta  = (const float*)d_in[6];
  const float* fc1w  = (const float*)d_in[7];
  const float* fc1b  = (const float*)d_in[8];
  const float* fc2w  = (const float*)d_in[9];
  const float* fc2b  = (const float*)d_in[10];
  const int*   ei    = (const int*)d_in[11];
  float* out = (float*)d_out;
  (void)in_sizes; (void)n_in; (void)out_size; (void)ws_size;

  char* p = (char*)d_ws;
  size_t off = 0;
  auto alloc = [&](size_t bytes) {
    char* q = p + off;
    off += (bytes + 255) & ~(size_t)255;
    return q;
  };
  int* hist    = (int*)alloc((size_t)NB * NBIN * 4);
  int* partial = (int*)alloc((size_t)NB * NBIN * 4);
  int* gtot    = (int*)alloc((size_t)NBIN * 4);
  int* gbase   = (int*)alloc((size_t)(NBIN + 1) * 4);
  unsigned long long* ebuf = (unsigned long long*)alloc((size_t)NE * 8);
  unsigned* ebuf2 = (unsigned*)alloc((size_t)NE * 4);
  int* rowptr  = (int*)alloc((size_t)(NN + 1) * 4);
  float* Se    = (float*)alloc((size_t)NN * CE * 4);
  int*   cnt   = (int*)alloc((size_t)NN * 4);
  __hip_bfloat16* ybuf = (__hip_bfloat16*)alloc((size_t)NN * HH * 2);
  __hip_bfloat16* zbuf = (__hip_bfloat16*)alloc((size_t)NN * HH * 2);
  __hip_bfloat16* xA   = (__hip_bfloat16*)alloc((size_t)NN * HH * 2);
  __hip_bfloat16* xB   = (__hip_bfloat16*)alloc((size_t)NN * HH * 2);
  float* emb   = (float*)alloc((size_t)3 * NG * HH * 4);
  float* pool  = (float*)alloc((size_t)NBIN * HH * 4);

  // CSR build via two-level counting sort (zero global atomics, no memsets)
  k_hist<<<NB, 256, 0, stream>>>(ei, hist);
  k_scan_a<<<NBIN, 256, 0, stream>>>(hist, partial, gtot);
  k_scan_b<<<1, 512, 0, stream>>>(gtot, gbase);
  k_bfill<<<NB, 256, 0, stream>>>(ei, partial, gbase, ebuf);
  k_nsort<<<NBIN, 256, 0, stream>>>(ebuf, gbase, ebuf2, rowptr, cnt);
  k_se3<<<SEB, 256, 0, stream>>>(ebuf2, rowptr, eattr, Se);

  // layer 0: x (f32) -> xA
  k_gemm<float><<<GB, 256, 0, stream>>>(x, W, b, cnt, Se, ybuf, zbuf);
  k_gath3<<<GTB, 256, 0, stream>>>(ybuf, zbuf, ebuf2, rowptr, gamma, beta, xA, emb);
  // layer 1: xA -> xB
  k_gemm<__hip_bfloat16><<<GB, 256, 0, stream>>>(xA, W + 144 * 64, b + 64, cnt, Se,
                                                 ybuf, zbuf);
  k_gath3<<<GTB, 256, 0, stream>>>(ybuf, zbuf, ebuf2, rowptr, gamma + 64, beta + 64,
                                   xB, emb + NG * HH);
  // layer 2: xB -> xA
  k_gemm<__hip_bfloat16><<<GB, 256, 0, stream>>>(xB, W + 2 * 144 * 64, b + 128, cnt,
                                                 Se, ybuf, zbuf);
  k_gath3<<<GTB, 256, 0, stream>>>(ybuf, zbuf, ebuf2, rowptr, gamma + 128, beta + 128,
                                   xA, emb + 2 * NG * HH);

  k_pool<<<NBIN, 512, 0, stream>>>(xA, pool);
  k_final<<<NG, 256, 0, stream>>>(pool, emb, nbr, fc1w, fc1b, fc2w, fc2b, out);
}